// Round 4
// baseline (685.814 us; speedup 1.0000x reference)
//
#include <hip/hip_runtime.h>
#include <math.h>

#define NEG_SLOPE 0.2f
#define EPS_C 1e-16f

__device__ __forceinline__ float lrelu(float x){ return x > 0.f ? x : NEG_SLOPE * x; }
__device__ __forceinline__ float eluf(float x){ return x > 0.f ? x : expm1f(x); }

// ---------------- CSR build (by dst) ----------------
__global__ void zero_int_kernel(int* __restrict__ p, int n){
  int i = blockIdx.x * blockDim.x + threadIdx.x;
  if (i < n) p[i] = 0;
}

__global__ void count_deg_kernel(const int* __restrict__ dst, int* __restrict__ deg, int E){
  int i = blockIdx.x * blockDim.x + threadIdx.x;
  if (i < E) atomicAdd(&deg[dst[i]], 1);
}

// one block, 1024 threads: exclusive scan of deg -> offsets, cursor
__global__ void scan_kernel(const int* __restrict__ deg, int* __restrict__ offsets,
                            int* __restrict__ cursor, int N){
  __shared__ int sums[1024];
  int t = threadIdx.x;
  int CH = (N + 1023) >> 10;
  int start = t * CH;
  int end = min(start + CH, N);
  int s = 0;
  for (int i = start; i < end; ++i) s += deg[i];
  sums[t] = s;
  __syncthreads();
  for (int st = 1; st < 1024; st <<= 1){
    int v = (t >= st) ? sums[t - st] : 0;
    __syncthreads();
    sums[t] += v;
    __syncthreads();
  }
  int prefix = (t == 0) ? 0 : sums[t - 1];
  for (int i = start; i < end; ++i){
    offsets[i] = prefix; cursor[i] = prefix; prefix += deg[i];
  }
  if (t == 1023) offsets[N] = sums[1023];
}

__global__ void scatter_kernel(const int* __restrict__ src, const int* __restrict__ dst,
                               int* __restrict__ cursor, int* __restrict__ csr_src,
                               int* __restrict__ csr_eid, int E){
  int i = blockIdx.x * blockDim.x + threadIdx.x;
  if (i < E){
    int d = dst[i];
    int p = atomicAdd(&cursor[d], 1);
    csr_src[p] = src[i];
    csr_eid[p] = i;
  }
}

// ---------------- layer 1 GEMM: h1 = x @ W1  [N,128]x[128,256] ----------------
// 128x64 tile, 8x4 micro-tile. col-block == head (64 ch), so the per-node
// attention dots for this head are block-exclusive: fused into the epilogue
// (saves a full 51 MB re-read of h1 by a separate att kernel).
__global__ __launch_bounds__(256) void gemm1_kernel(const float* __restrict__ x,
    const float* __restrict__ W, const float* __restrict__ att_src,
    const float* __restrict__ att_dst, float* __restrict__ h1,
    float* __restrict__ a_src_f, float* __restrict__ a_dst_f, int N){
  __shared__ float As[128][33];
  __shared__ float Bs[32][65];
  int tid = threadIdx.x;
  int tx = tid & 15, ty = tid >> 4;
  int rowBase = blockIdx.x * 128;
  int head = blockIdx.y;          // col block == head
  int colBase = head * 64;
  float acc[8][4] = {};
  for (int k0 = 0; k0 < 128; k0 += 32){
    // A tile: 128x32 = 4096 floats = 4 float4 per thread
    #pragma unroll
    for (int it = 0; it < 4; ++it){
      int li = it * 256 + tid;
      int r = li >> 3;
      int kk = (li & 7) << 2;
      int row = rowBase + r;
      float4 v = make_float4(0.f, 0.f, 0.f, 0.f);
      if (row < N) v = *reinterpret_cast<const float4*>(&x[(size_t)row * 128 + k0 + kk]);
      As[r][kk] = v.x; As[r][kk + 1] = v.y; As[r][kk + 2] = v.z; As[r][kk + 3] = v.w;
    }
    // B tile: 32x64 = 2048 floats = 2 float4 per thread
    #pragma unroll
    for (int it = 0; it < 2; ++it){
      int li = it * 256 + tid;
      int kr = li >> 4;
      int c4 = (li & 15) << 2;
      float4 v = *reinterpret_cast<const float4*>(&W[(size_t)(k0 + kr) * 256 + colBase + c4]);
      Bs[kr][c4] = v.x; Bs[kr][c4 + 1] = v.y; Bs[kr][c4 + 2] = v.z; Bs[kr][c4 + 3] = v.w;
    }
    __syncthreads();
    #pragma unroll
    for (int kk = 0; kk < 32; ++kk){
      float4 b = make_float4(Bs[kk][tx * 4], Bs[kk][tx * 4 + 1],
                             Bs[kk][tx * 4 + 2], Bs[kk][tx * 4 + 3]);
      #pragma unroll
      for (int j = 0; j < 8; ++j){
        float a = As[ty + 16 * j][kk];
        acc[j][0] += a * b.x; acc[j][1] += a * b.y;
        acc[j][2] += a * b.z; acc[j][3] += a * b.w;
      }
    }
    __syncthreads();
  }
  // store h1 tile
  #pragma unroll
  for (int j = 0; j < 8; ++j){
    int row = rowBase + ty + 16 * j;
    if (row < N)
      *reinterpret_cast<float4*>(&h1[(size_t)row * 256 + colBase + tx * 4]) =
          make_float4(acc[j][0], acc[j][1], acc[j][2], acc[j][3]);
  }
  // fused attention dots for this head: reduce acc over columns.
  float4 s4 = *reinterpret_cast<const float4*>(&att_src[colBase + tx * 4]);
  float4 d4 = *reinterpret_cast<const float4*>(&att_dst[colBase + tx * 4]);
  float ps[8], pd[8];
  #pragma unroll
  for (int j = 0; j < 8; ++j){
    ps[j] = acc[j][0] * s4.x + acc[j][1] * s4.y + acc[j][2] * s4.z + acc[j][3] * s4.w;
    pd[j] = acc[j][0] * d4.x + acc[j][1] * d4.y + acc[j][2] * d4.z + acc[j][3] * d4.w;
  }
  // butterfly over the 16-lane tx group (xor 1/2/4/8 stays in-group)
  #pragma unroll
  for (int st = 8; st > 0; st >>= 1){
    #pragma unroll
    for (int j = 0; j < 8; ++j){
      ps[j] += __shfl_xor(ps[j], st);
      pd[j] += __shfl_xor(pd[j], st);
    }
  }
  if (tx == 0){
    #pragma unroll
    for (int j = 0; j < 8; ++j){
      int row = rowBase + ty + 16 * j;
      if (row < N){
        a_src_f[(size_t)row * 4 + head] = ps[j];
        a_dst_f[(size_t)row * 4 + head] = pd[j];
      }
    }
  }
}

// ---------------- layer 1 node kernel: softmax + aggregate + bias + ELU ----------------
// Slot-0 attention logits cached in registers: with mean deg 16 (sigma~4),
// deg<=64 for essentially all nodes, so passes 2/3 need no re-gather.
// Fallback strided loops keep exactness for arbitrary degree.
__global__ __launch_bounds__(256) void node1_kernel(
    const float* __restrict__ h1, const float4* __restrict__ a_src,
    const float* __restrict__ a_src_f, const float4* __restrict__ a_dst,
    const int* __restrict__ offsets, const int* __restrict__ csr_src,
    const int* __restrict__ csr_eid, const float* __restrict__ bias,
    float* __restrict__ h1b, float* __restrict__ alpha1_out, int N){
  int gid = blockIdx.x * blockDim.x + threadIdx.x;
  int n = gid >> 6, lane = gid & 63;
  if (n >= N) return;
  int off = offsets[n];
  int deg = offsets[n + 1] - off;
  float4 ad = a_dst[n];
  // pass 1: max (cache slot-0 logits)
  bool have0 = (lane < deg);
  float4 e0 = make_float4(-INFINITY, -INFINITY, -INFINITY, -INFINITY);
  if (have0){
    float4 as = a_src[csr_src[off + lane]];
    e0 = make_float4(lrelu(as.x + ad.x), lrelu(as.y + ad.y),
                     lrelu(as.z + ad.z), lrelu(as.w + ad.w));
  }
  float m0 = e0.x, m1 = e0.y, m2 = e0.z, m3 = e0.w;
  for (int i = lane + 64; i < deg; i += 64){
    float4 as = a_src[csr_src[off + i]];
    m0 = fmaxf(m0, lrelu(as.x + ad.x));
    m1 = fmaxf(m1, lrelu(as.y + ad.y));
    m2 = fmaxf(m2, lrelu(as.z + ad.z));
    m3 = fmaxf(m3, lrelu(as.w + ad.w));
  }
  #pragma unroll
  for (int st = 32; st > 0; st >>= 1){
    m0 = fmaxf(m0, __shfl_xor(m0, st));
    m1 = fmaxf(m1, __shfl_xor(m1, st));
    m2 = fmaxf(m2, __shfl_xor(m2, st));
    m3 = fmaxf(m3, __shfl_xor(m3, st));
  }
  // pass 2: sum (slot 0 from cache)
  float s0 = 0.f, s1 = 0.f, s2 = 0.f, s3 = 0.f;
  if (have0){
    s0 = __expf(e0.x - m0); s1 = __expf(e0.y - m1);
    s2 = __expf(e0.z - m2); s3 = __expf(e0.w - m3);
  }
  for (int i = lane + 64; i < deg; i += 64){
    float4 as = a_src[csr_src[off + i]];
    s0 += __expf(lrelu(as.x + ad.x) - m0);
    s1 += __expf(lrelu(as.y + ad.y) - m1);
    s2 += __expf(lrelu(as.z + ad.z) - m2);
    s3 += __expf(lrelu(as.w + ad.w) - m3);
  }
  #pragma unroll
  for (int st = 32; st > 0; st >>= 1){
    s0 += __shfl_xor(s0, st); s1 += __shfl_xor(s1, st);
    s2 += __shfl_xor(s2, st); s3 += __shfl_xor(s3, st);
  }
  float i0 = 1.f / (s0 + EPS_C), i1 = 1.f / (s1 + EPS_C);
  float i2 = 1.f / (s2 + EPS_C), i3 = 1.f / (s3 + EPS_C);
  // pass 3: alpha write in original edge order (slot 0 from cache)
  if (have0){
    int eid = csr_eid[off + lane];
    *reinterpret_cast<float4*>(&alpha1_out[(size_t)eid * 4]) =
        make_float4(__expf(e0.x - m0) * i0, __expf(e0.y - m1) * i1,
                    __expf(e0.z - m2) * i2, __expf(e0.w - m3) * i3);
  }
  for (int i = lane + 64; i < deg; i += 64){
    int slot = off + i;
    float4 as = a_src[csr_src[slot]];
    int eid = csr_eid[slot];
    *reinterpret_cast<float4*>(&alpha1_out[(size_t)eid * 4]) =
        make_float4(__expf(lrelu(as.x + ad.x) - m0) * i0,
                    __expf(lrelu(as.y + ad.y) - m1) * i1,
                    __expf(lrelu(as.z + ad.z) - m2) * i2,
                    __expf(lrelu(as.w + ad.w) - m3) * i3);
  }
  // aggregation: lane owns channels [4*lane, 4*lane+3]; head = lane>>4.
  // Unroll x4 with independent accumulators for gather MLP.
  int head = lane >> 4;
  float mh  = head == 0 ? m0 : head == 1 ? m1 : head == 2 ? m2 : m3;
  float ih  = head == 0 ? i0 : head == 1 ? i1 : head == 2 ? i2 : i3;
  float adh = head == 0 ? ad.x : head == 1 ? ad.y : head == 2 ? ad.z : ad.w;
  float4 accA = make_float4(0.f, 0.f, 0.f, 0.f);
  float4 accB = make_float4(0.f, 0.f, 0.f, 0.f);
  float4 accC = make_float4(0.f, 0.f, 0.f, 0.f);
  float4 accD = make_float4(0.f, 0.f, 0.f, 0.f);
  int j = 0;
  for (; j + 3 < deg; j += 4){
    int sA = csr_src[off + j];
    int sB = csr_src[off + j + 1];
    int sC = csr_src[off + j + 2];
    int sD = csr_src[off + j + 3];
    float alA = __expf(lrelu(a_src_f[(size_t)sA * 4 + head] + adh) - mh) * ih;
    float alB = __expf(lrelu(a_src_f[(size_t)sB * 4 + head] + adh) - mh) * ih;
    float alC = __expf(lrelu(a_src_f[(size_t)sC * 4 + head] + adh) - mh) * ih;
    float alD = __expf(lrelu(a_src_f[(size_t)sD * 4 + head] + adh) - mh) * ih;
    float4 hA = *reinterpret_cast<const float4*>(&h1[(size_t)sA * 256 + lane * 4]);
    float4 hB = *reinterpret_cast<const float4*>(&h1[(size_t)sB * 256 + lane * 4]);
    float4 hC = *reinterpret_cast<const float4*>(&h1[(size_t)sC * 256 + lane * 4]);
    float4 hD = *reinterpret_cast<const float4*>(&h1[(size_t)sD * 256 + lane * 4]);
    accA.x += alA * hA.x; accA.y += alA * hA.y; accA.z += alA * hA.z; accA.w += alA * hA.w;
    accB.x += alB * hB.x; accB.y += alB * hB.y; accB.z += alB * hB.z; accB.w += alB * hB.w;
    accC.x += alC * hC.x; accC.y += alC * hC.y; accC.z += alC * hC.z; accC.w += alC * hC.w;
    accD.x += alD * hD.x; accD.y += alD * hD.y; accD.z += alD * hD.z; accD.w += alD * hD.w;
  }
  for (; j < deg; ++j){
    int sA = csr_src[off + j];
    float alA = __expf(lrelu(a_src_f[(size_t)sA * 4 + head] + adh) - mh) * ih;
    float4 hA = *reinterpret_cast<const float4*>(&h1[(size_t)sA * 256 + lane * 4]);
    accA.x += alA * hA.x; accA.y += alA * hA.y; accA.z += alA * hA.z; accA.w += alA * hA.w;
  }
  accA.x += accB.x + accC.x + accD.x;
  accA.y += accB.y + accC.y + accD.y;
  accA.z += accB.z + accC.z + accD.z;
  accA.w += accB.w + accC.w + accD.w;
  float4 b = *reinterpret_cast<const float4*>(&bias[lane * 4]);
  float4 o = make_float4(eluf(accA.x + b.x), eluf(accA.y + b.y),
                         eluf(accA.z + b.z), eluf(accA.w + b.w));
  *reinterpret_cast<float4*>(&h1b[(size_t)n * 256 + lane * 4]) = o;
}

// ---------------- layer 2 GEMM + attention dots (wave per node) ----------------
__global__ __launch_bounds__(256) void gemm2_kernel(const float* __restrict__ h1b,
    const float* __restrict__ W2, const float* __restrict__ att_src2,
    const float* __restrict__ att_dst2, float* __restrict__ h2pre,
    float* __restrict__ a_src2, float* __restrict__ a_dst2, int N){
  __shared__ float W2s[256 * 32];
  for (int i = threadIdx.x; i < 256 * 32; i += 256) W2s[i] = W2[i];
  __syncthreads();
  int gid = blockIdx.x * blockDim.x + threadIdx.x;
  int n = gid >> 6, lane = gid & 63;
  if (n >= N) return;
  int c = lane & 31, half = lane >> 5;
  const float* hrow = h1b + (size_t)n * 256;
  float acc = 0.f;
  int kbase = half * 128;
  for (int k = 0; k < 128; ++k)
    acc += hrow[kbase + k] * W2s[(kbase + k) * 32 + c];
  acc += __shfl_xor(acc, 32);
  float asv = acc * att_src2[c];
  float adv = acc * att_dst2[c];
  #pragma unroll
  for (int st = 16; st > 0; st >>= 1){ asv += __shfl_xor(asv, st); adv += __shfl_xor(adv, st); }
  if (lane < 32) h2pre[(size_t)n * 32 + c] = acc;
  if (lane == 0){ a_src2[n] = asv; a_dst2[n] = adv; }
}

// ---------------- layer 2 node kernel: softmax + aggregate + bias ----------------
__global__ __launch_bounds__(256) void node2_kernel(
    const float* __restrict__ h2pre, const float* __restrict__ a_src2,
    const float* __restrict__ a_dst2, const int* __restrict__ offsets,
    const int* __restrict__ csr_src, const int* __restrict__ csr_eid,
    const float* __restrict__ bias2, float* __restrict__ out_h2,
    float* __restrict__ alpha2_out, int N){
  int gid = blockIdx.x * blockDim.x + threadIdx.x;
  int n = gid >> 6, lane = gid & 63;
  if (n >= N) return;
  int off = offsets[n], deg = offsets[n + 1] - off;
  float adn = a_dst2[n];
  bool have0 = (lane < deg);
  float e0 = -INFINITY;
  if (have0) e0 = lrelu(a_src2[csr_src[off + lane]] + adn);
  float m = e0;
  for (int i = lane + 64; i < deg; i += 64)
    m = fmaxf(m, lrelu(a_src2[csr_src[off + i]] + adn));
  #pragma unroll
  for (int st = 32; st > 0; st >>= 1) m = fmaxf(m, __shfl_xor(m, st));
  float s = have0 ? __expf(e0 - m) : 0.f;
  for (int i = lane + 64; i < deg; i += 64)
    s += __expf(lrelu(a_src2[csr_src[off + i]] + adn) - m);
  #pragma unroll
  for (int st = 32; st > 0; st >>= 1) s += __shfl_xor(s, st);
  float inv = 1.f / (s + EPS_C);
  if (have0) alpha2_out[csr_eid[off + lane]] = __expf(e0 - m) * inv;
  for (int i = lane + 64; i < deg; i += 64){
    int slot = off + i;
    alpha2_out[csr_eid[slot]] = __expf(lrelu(a_src2[csr_src[slot]] + adn) - m) * inv;
  }
  int c = lane & 31, half = lane >> 5;
  float acc = 0.f;
  for (int j = half; j < deg; j += 2){
    int src = csr_src[off + j];
    float al = __expf(lrelu(a_src2[src] + adn) - m) * inv;
    acc += al * h2pre[(size_t)src * 32 + c];
  }
  acc += __shfl_xor(acc, 32);
  if (lane < 32) out_h2[(size_t)n * 32 + c] = acc + bias2[c];
}

// ---------------- echo edge_index (as float) into output regions 1 and 3 ----------------
__global__ void edge_out_kernel(const int* __restrict__ ei, float* __restrict__ out1,
                                float* __restrict__ out3, int n2e){
  int i = blockIdx.x * blockDim.x + threadIdx.x;
  if (i < n2e){
    float v = (float)ei[i];
    out1[i] = v; out3[i] = v;
  }
}

extern "C" void kernel_launch(void* const* d_in, const int* in_sizes, int n_in,
                              void* d_out, int out_size, void* d_ws, size_t ws_size,
                              hipStream_t stream){
  const float* x        = (const float*)d_in[0];
  const int*   ei       = (const int*)d_in[1];
  const float* W1       = (const float*)d_in[2];
  const float* att_src1 = (const float*)d_in[3];
  const float* att_dst1 = (const float*)d_in[4];
  const float* bias1    = (const float*)d_in[5];
  const float* W2       = (const float*)d_in[6];
  const float* att_src2 = (const float*)d_in[7];
  const float* att_dst2 = (const float*)d_in[8];
  const float* bias2    = (const float*)d_in[9];
  float* out = (float*)d_out;
  (void)n_in; (void)out_size; (void)ws_size;

  const int N = in_sizes[0] / 128;
  const int E = in_sizes[1] / 2;
  const int* src = ei;
  const int* dst = ei + E;

  char* ws = (char*)d_ws;
  size_t o = 0;
  auto alloc = [&](size_t bytes) -> void* {
    void* p = ws + o;
    o += (bytes + 255) & ~(size_t)255;
    return p;
  };
  float*  h1      = (float*)alloc((size_t)N * 256 * 4);
  float*  h1b     = (float*)alloc((size_t)N * 256 * 4);
  float*  h2pre   = (float*)alloc((size_t)N * 32 * 4);
  float*  a_src1  = (float*)alloc((size_t)N * 16);
  float*  a_dst1  = (float*)alloc((size_t)N * 16);
  float*  a_src2  = (float*)alloc((size_t)N * 4);
  float*  a_dst2  = (float*)alloc((size_t)N * 4);
  int*    deg     = (int*)alloc((size_t)N * 4);
  int*    offsets = (int*)alloc((size_t)(N + 1) * 4);
  int*    cursor  = (int*)alloc((size_t)N * 4);
  int*    csr_src = (int*)alloc((size_t)E * 4);
  int*    csr_eid = (int*)alloc((size_t)E * 4);

  const size_t OFF1 = (size_t)N * 32;       // edge_index copy 1
  const size_t OFF2 = OFF1 + (size_t)2 * E; // alpha1 [E,4]
  const size_t OFF3 = OFF2 + (size_t)E * 4; // edge_index copy 2
  const size_t OFF4 = OFF3 + (size_t)2 * E; // alpha2 [E]

  // CSR build
  hipLaunchKernelGGL(zero_int_kernel, dim3((N + 255) / 256), dim3(256), 0, stream, deg, N);
  hipLaunchKernelGGL(count_deg_kernel, dim3((E + 255) / 256), dim3(256), 0, stream, dst, deg, E);
  hipLaunchKernelGGL(scan_kernel, dim3(1), dim3(1024), 0, stream, deg, offsets, cursor, N);
  hipLaunchKernelGGL(scatter_kernel, dim3((E + 255) / 256), dim3(256), 0, stream,
                     src, dst, cursor, csr_src, csr_eid, E);
  // layer 1 (attention dots fused into GEMM epilogue)
  hipLaunchKernelGGL(gemm1_kernel, dim3((N + 127) / 128, 4), dim3(256), 0, stream,
                     x, W1, att_src1, att_dst1, h1, a_src1, a_dst1, N);
  hipLaunchKernelGGL(node1_kernel, dim3((N * 64 + 255) / 256), dim3(256), 0, stream,
                     h1, (const float4*)a_src1, (const float*)a_src1, (const float4*)a_dst1,
                     offsets, csr_src, csr_eid, bias1, h1b, out + OFF2, N);
  // layer 2
  hipLaunchKernelGGL(gemm2_kernel, dim3((N * 64 + 255) / 256), dim3(256), 0, stream,
                     h1b, W2, att_src2, att_dst2, h2pre, a_src2, a_dst2, N);
  hipLaunchKernelGGL(node2_kernel, dim3((N * 64 + 255) / 256), dim3(256), 0, stream,
                     h2pre, a_src2, a_dst2, offsets, csr_src, csr_eid, bias2,
                     out, out + OFF4, N);
  // edge_index echo
  hipLaunchKernelGGL(edge_out_kernel, dim3((2 * E + 255) / 256), dim3(256), 0, stream,
                     ei, out + OFF1, out + OFF3, 2 * E);
}

// Round 5
// 616.381 us; speedup vs baseline: 1.1126x; 1.1126x over previous
//
#include <hip/hip_runtime.h>
#include <math.h>

#define NEG_SLOPE 0.2f
#define EPS_C 1e-16f

__device__ __forceinline__ float lrelu(float x){ return x > 0.f ? x : NEG_SLOPE * x; }
__device__ __forceinline__ float eluf(float x){ return x > 0.f ? x : expm1f(x); }

// ---------------- CSR build (by dst) ----------------
__global__ void zero_int_kernel(int* __restrict__ p, int n){
  int i = blockIdx.x * blockDim.x + threadIdx.x;
  if (i < n) p[i] = 0;
}

__global__ void count_deg_kernel(const int* __restrict__ dst, int* __restrict__ deg, int E){
  int i = blockIdx.x * blockDim.x + threadIdx.x;
  if (i < E) atomicAdd(&deg[dst[i]], 1);
}

// one block, 1024 threads: exclusive scan of deg -> offsets, cursor
__global__ void scan_kernel(const int* __restrict__ deg, int* __restrict__ offsets,
                            int* __restrict__ cursor, int N){
  __shared__ int sums[1024];
  int t = threadIdx.x;
  int CH = (N + 1023) >> 10;
  int start = t * CH;
  int end = min(start + CH, N);
  int s = 0;
  for (int i = start; i < end; ++i) s += deg[i];
  sums[t] = s;
  __syncthreads();
  for (int st = 1; st < 1024; st <<= 1){
    int v = (t >= st) ? sums[t - st] : 0;
    __syncthreads();
    sums[t] += v;
    __syncthreads();
  }
  int prefix = (t == 0) ? 0 : sums[t - 1];
  for (int i = start; i < end; ++i){
    offsets[i] = prefix; cursor[i] = prefix; prefix += deg[i];
  }
  if (t == 1023) offsets[N] = sums[1023];
}

__global__ void scatter_kernel(const int* __restrict__ src, const int* __restrict__ dst,
                               int* __restrict__ cursor, int* __restrict__ csr_src,
                               int* __restrict__ csr_eid, int E){
  int i = blockIdx.x * blockDim.x + threadIdx.x;
  if (i < E){
    int d = dst[i];
    int p = atomicAdd(&cursor[d], 1);
    csr_src[p] = src[i];
    csr_eid[p] = i;
  }
}

// ---------------- layer 1 GEMM: h1 = x @ W1  [N,128]x[128,256] ----------------
// 128x64 tile, 8x4 micro-tile, attention dots fused in epilogue.
// R4 counters: 155us, VALUBusy 18%, occupancy 10% -> latency-bound on the
// per-K-chunk load->LDS->barrier drain. Fix: software pipeline (G->reg
// prefetch of chunk k0+32 issued before compute of k0, regs->LDS after
// barrier). Single LDS buffer, 2 barriers per chunk.
__global__ __launch_bounds__(256) void gemm1_kernel(const float* __restrict__ x,
    const float* __restrict__ W, const float* __restrict__ att_src,
    const float* __restrict__ att_dst, float* __restrict__ h1,
    float* __restrict__ a_src_f, float* __restrict__ a_dst_f, int N){
  __shared__ float As[128][33];
  __shared__ float Bs[32][65];
  int tid = threadIdx.x;
  int tx = tid & 15, ty = tid >> 4;
  int rowBase = blockIdx.x * 128;
  int head = blockIdx.y;          // col block == head
  int colBase = head * 64;
  float acc[8][4] = {};
  float4 pa[4], pb[2];

  // load chunk 0 into regs
  #pragma unroll
  for (int it = 0; it < 4; ++it){
    int li = it * 256 + tid;
    int r = li >> 3, kk = (li & 7) << 2;
    int row = rowBase + r;
    pa[it] = (row < N) ? *reinterpret_cast<const float4*>(&x[(size_t)row * 128 + kk])
                       : make_float4(0.f, 0.f, 0.f, 0.f);
  }
  #pragma unroll
  for (int it = 0; it < 2; ++it){
    int li = it * 256 + tid;
    int kr = li >> 4, c4 = (li & 15) << 2;
    pb[it] = *reinterpret_cast<const float4*>(&W[(size_t)kr * 256 + colBase + c4]);
  }
  // store chunk 0
  #pragma unroll
  for (int it = 0; it < 4; ++it){
    int li = it * 256 + tid;
    int r = li >> 3, kk = (li & 7) << 2;
    As[r][kk] = pa[it].x; As[r][kk + 1] = pa[it].y;
    As[r][kk + 2] = pa[it].z; As[r][kk + 3] = pa[it].w;
  }
  #pragma unroll
  for (int it = 0; it < 2; ++it){
    int li = it * 256 + tid;
    int kr = li >> 4, c4 = (li & 15) << 2;
    Bs[kr][c4] = pb[it].x; Bs[kr][c4 + 1] = pb[it].y;
    Bs[kr][c4 + 2] = pb[it].z; Bs[kr][c4 + 3] = pb[it].w;
  }
  __syncthreads();

  for (int k0 = 0; k0 < 128; k0 += 32){
    bool more = (k0 + 32) < 128;
    if (more){
      // issue next chunk's loads; first use is after the next barrier,
      // so their latency hides under this chunk's compute.
      #pragma unroll
      for (int it = 0; it < 4; ++it){
        int li = it * 256 + tid;
        int r = li >> 3, kk = (li & 7) << 2;
        int row = rowBase + r;
        pa[it] = (row < N) ? *reinterpret_cast<const float4*>(&x[(size_t)row * 128 + k0 + 32 + kk])
                           : make_float4(0.f, 0.f, 0.f, 0.f);
      }
      #pragma unroll
      for (int it = 0; it < 2; ++it){
        int li = it * 256 + tid;
        int kr = li >> 4, c4 = (li & 15) << 2;
        pb[it] = *reinterpret_cast<const float4*>(&W[(size_t)(k0 + 32 + kr) * 256 + colBase + c4]);
      }
    }
    #pragma unroll
    for (int kk = 0; kk < 32; ++kk){
      float4 b = make_float4(Bs[kk][tx * 4], Bs[kk][tx * 4 + 1],
                             Bs[kk][tx * 4 + 2], Bs[kk][tx * 4 + 3]);
      #pragma unroll
      for (int j = 0; j < 8; ++j){
        float a = As[ty + 16 * j][kk];
        acc[j][0] += a * b.x; acc[j][1] += a * b.y;
        acc[j][2] += a * b.z; acc[j][3] += a * b.w;
      }
    }
    if (more){
      __syncthreads();   // all waves done reading the buffer
      #pragma unroll
      for (int it = 0; it < 4; ++it){
        int li = it * 256 + tid;
        int r = li >> 3, kk = (li & 7) << 2;
        As[r][kk] = pa[it].x; As[r][kk + 1] = pa[it].y;
        As[r][kk + 2] = pa[it].z; As[r][kk + 3] = pa[it].w;
      }
      #pragma unroll
      for (int it = 0; it < 2; ++it){
        int li = it * 256 + tid;
        int kr = li >> 4, c4 = (li & 15) << 2;
        Bs[kr][c4] = pb[it].x; Bs[kr][c4 + 1] = pb[it].y;
        Bs[kr][c4 + 2] = pb[it].z; Bs[kr][c4 + 3] = pb[it].w;
      }
      __syncthreads();   // new chunk visible
    }
  }
  // store h1 tile
  #pragma unroll
  for (int j = 0; j < 8; ++j){
    int row = rowBase + ty + 16 * j;
    if (row < N)
      *reinterpret_cast<float4*>(&h1[(size_t)row * 256 + colBase + tx * 4]) =
          make_float4(acc[j][0], acc[j][1], acc[j][2], acc[j][3]);
  }
  // fused attention dots for this head: reduce acc over columns.
  float4 s4 = *reinterpret_cast<const float4*>(&att_src[colBase + tx * 4]);
  float4 d4 = *reinterpret_cast<const float4*>(&att_dst[colBase + tx * 4]);
  float ps[8], pd[8];
  #pragma unroll
  for (int j = 0; j < 8; ++j){
    ps[j] = acc[j][0] * s4.x + acc[j][1] * s4.y + acc[j][2] * s4.z + acc[j][3] * s4.w;
    pd[j] = acc[j][0] * d4.x + acc[j][1] * d4.y + acc[j][2] * d4.z + acc[j][3] * d4.w;
  }
  #pragma unroll
  for (int st = 8; st > 0; st >>= 1){
    #pragma unroll
    for (int j = 0; j < 8; ++j){
      ps[j] += __shfl_xor(ps[j], st);
      pd[j] += __shfl_xor(pd[j], st);
    }
  }
  if (tx == 0){
    #pragma unroll
    for (int j = 0; j < 8; ++j){
      int row = rowBase + ty + 16 * j;
      if (row < N){
        a_src_f[(size_t)row * 4 + head] = ps[j];
        a_dst_f[(size_t)row * 4 + head] = pd[j];
      }
    }
  }
}

// ---------------- layer 1 node kernel: softmax + aggregate + bias + ELU ----------------
__global__ __launch_bounds__(256) void node1_kernel(
    const float* __restrict__ h1, const float4* __restrict__ a_src,
    const float* __restrict__ a_src_f, const float4* __restrict__ a_dst,
    const int* __restrict__ offsets, const int* __restrict__ csr_src,
    const int* __restrict__ csr_eid, const float* __restrict__ bias,
    float* __restrict__ h1b, float* __restrict__ alpha1_out, int N){
  int gid = blockIdx.x * blockDim.x + threadIdx.x;
  int n = gid >> 6, lane = gid & 63;
  if (n >= N) return;
  int off = offsets[n];
  int deg = offsets[n + 1] - off;
  float4 ad = a_dst[n];
  // pass 1: max (cache slot-0 logits)
  bool have0 = (lane < deg);
  float4 e0 = make_float4(-INFINITY, -INFINITY, -INFINITY, -INFINITY);
  if (have0){
    float4 as = a_src[csr_src[off + lane]];
    e0 = make_float4(lrelu(as.x + ad.x), lrelu(as.y + ad.y),
                     lrelu(as.z + ad.z), lrelu(as.w + ad.w));
  }
  float m0 = e0.x, m1 = e0.y, m2 = e0.z, m3 = e0.w;
  for (int i = lane + 64; i < deg; i += 64){
    float4 as = a_src[csr_src[off + i]];
    m0 = fmaxf(m0, lrelu(as.x + ad.x));
    m1 = fmaxf(m1, lrelu(as.y + ad.y));
    m2 = fmaxf(m2, lrelu(as.z + ad.z));
    m3 = fmaxf(m3, lrelu(as.w + ad.w));
  }
  #pragma unroll
  for (int st = 32; st > 0; st >>= 1){
    m0 = fmaxf(m0, __shfl_xor(m0, st));
    m1 = fmaxf(m1, __shfl_xor(m1, st));
    m2 = fmaxf(m2, __shfl_xor(m2, st));
    m3 = fmaxf(m3, __shfl_xor(m3, st));
  }
  // pass 2: sum (slot 0 from cache)
  float s0 = 0.f, s1 = 0.f, s2 = 0.f, s3 = 0.f;
  if (have0){
    s0 = __expf(e0.x - m0); s1 = __expf(e0.y - m1);
    s2 = __expf(e0.z - m2); s3 = __expf(e0.w - m3);
  }
  for (int i = lane + 64; i < deg; i += 64){
    float4 as = a_src[csr_src[off + i]];
    s0 += __expf(lrelu(as.x + ad.x) - m0);
    s1 += __expf(lrelu(as.y + ad.y) - m1);
    s2 += __expf(lrelu(as.z + ad.z) - m2);
    s3 += __expf(lrelu(as.w + ad.w) - m3);
  }
  #pragma unroll
  for (int st = 32; st > 0; st >>= 1){
    s0 += __shfl_xor(s0, st); s1 += __shfl_xor(s1, st);
    s2 += __shfl_xor(s2, st); s3 += __shfl_xor(s3, st);
  }
  float i0 = 1.f / (s0 + EPS_C), i1 = 1.f / (s1 + EPS_C);
  float i2 = 1.f / (s2 + EPS_C), i3 = 1.f / (s3 + EPS_C);
  // pass 3: alpha write in original edge order (slot 0 from cache)
  if (have0){
    int eid = csr_eid[off + lane];
    *reinterpret_cast<float4*>(&alpha1_out[(size_t)eid * 4]) =
        make_float4(__expf(e0.x - m0) * i0, __expf(e0.y - m1) * i1,
                    __expf(e0.z - m2) * i2, __expf(e0.w - m3) * i3);
  }
  for (int i = lane + 64; i < deg; i += 64){
    int slot = off + i;
    float4 as = a_src[csr_src[slot]];
    int eid = csr_eid[slot];
    *reinterpret_cast<float4*>(&alpha1_out[(size_t)eid * 4]) =
        make_float4(__expf(lrelu(as.x + ad.x) - m0) * i0,
                    __expf(lrelu(as.y + ad.y) - m1) * i1,
                    __expf(lrelu(as.z + ad.z) - m2) * i2,
                    __expf(lrelu(as.w + ad.w) - m3) * i3);
  }
  // aggregation: lane owns channels [4*lane, 4*lane+3]; head = lane>>4.
  int head = lane >> 4;
  float mh  = head == 0 ? m0 : head == 1 ? m1 : head == 2 ? m2 : m3;
  float ih  = head == 0 ? i0 : head == 1 ? i1 : head == 2 ? i2 : i3;
  float adh = head == 0 ? ad.x : head == 1 ? ad.y : head == 2 ? ad.z : ad.w;
  float4 accA = make_float4(0.f, 0.f, 0.f, 0.f);
  float4 accB = make_float4(0.f, 0.f, 0.f, 0.f);
  float4 accC = make_float4(0.f, 0.f, 0.f, 0.f);
  float4 accD = make_float4(0.f, 0.f, 0.f, 0.f);
  int j = 0;
  for (; j + 3 < deg; j += 4){
    int sA = csr_src[off + j];
    int sB = csr_src[off + j + 1];
    int sC = csr_src[off + j + 2];
    int sD = csr_src[off + j + 3];
    float alA = __expf(lrelu(a_src_f[(size_t)sA * 4 + head] + adh) - mh) * ih;
    float alB = __expf(lrelu(a_src_f[(size_t)sB * 4 + head] + adh) - mh) * ih;
    float alC = __expf(lrelu(a_src_f[(size_t)sC * 4 + head] + adh) - mh) * ih;
    float alD = __expf(lrelu(a_src_f[(size_t)sD * 4 + head] + adh) - mh) * ih;
    float4 hA = *reinterpret_cast<const float4*>(&h1[(size_t)sA * 256 + lane * 4]);
    float4 hB = *reinterpret_cast<const float4*>(&h1[(size_t)sB * 256 + lane * 4]);
    float4 hC = *reinterpret_cast<const float4*>(&h1[(size_t)sC * 256 + lane * 4]);
    float4 hD = *reinterpret_cast<const float4*>(&h1[(size_t)sD * 256 + lane * 4]);
    accA.x += alA * hA.x; accA.y += alA * hA.y; accA.z += alA * hA.z; accA.w += alA * hA.w;
    accB.x += alB * hB.x; accB.y += alB * hB.y; accB.z += alB * hB.z; accB.w += alB * hB.w;
    accC.x += alC * hC.x; accC.y += alC * hC.y; accC.z += alC * hC.z; accC.w += alC * hC.w;
    accD.x += alD * hD.x; accD.y += alD * hD.y; accD.z += alD * hD.z; accD.w += alD * hD.w;
  }
  for (; j < deg; ++j){
    int sA = csr_src[off + j];
    float alA = __expf(lrelu(a_src_f[(size_t)sA * 4 + head] + adh) - mh) * ih;
    float4 hA = *reinterpret_cast<const float4*>(&h1[(size_t)sA * 256 + lane * 4]);
    accA.x += alA * hA.x; accA.y += alA * hA.y; accA.z += alA * hA.z; accA.w += alA * hA.w;
  }
  accA.x += accB.x + accC.x + accD.x;
  accA.y += accB.y + accC.y + accD.y;
  accA.z += accB.z + accC.z + accD.z;
  accA.w += accB.w + accC.w + accD.w;
  float4 b = *reinterpret_cast<const float4*>(&bias[lane * 4]);
  float4 o = make_float4(eluf(accA.x + b.x), eluf(accA.y + b.y),
                         eluf(accA.z + b.z), eluf(accA.w + b.w));
  *reinterpret_cast<float4*>(&h1b[(size_t)n * 256 + lane * 4]) = o;
}

// ---------------- layer 2 GEMM: h2pre = h1b @ W2 [N,256]x[256,32] ----------------
// Proper tiled GEMM (old version staged 32 KB of W2 per 4-node block ~= 400 MB
// of L2 restaging). 128x32 tile, 8x2 micro-tile, att2 dots fused in epilogue,
// same K-prefetch pipeline as gemm1.
__global__ __launch_bounds__(256) void gemm2_kernel(const float* __restrict__ h1b,
    const float* __restrict__ W2, const float* __restrict__ att_src2,
    const float* __restrict__ att_dst2, float* __restrict__ h2pre,
    float* __restrict__ a_src2, float* __restrict__ a_dst2, int N){
  __shared__ float As[128][33];
  __shared__ float Bs[32][33];
  int tid = threadIdx.x;
  int tx = tid & 15, ty = tid >> 4;
  int rowBase = blockIdx.x * 128;
  float acc[8][2] = {};
  float4 pa[4], pb;

  // load chunk 0
  #pragma unroll
  for (int it = 0; it < 4; ++it){
    int li = it * 256 + tid;
    int r = li >> 3, kk = (li & 7) << 2;
    int row = rowBase + r;
    pa[it] = (row < N) ? *reinterpret_cast<const float4*>(&h1b[(size_t)row * 256 + kk])
                       : make_float4(0.f, 0.f, 0.f, 0.f);
  }
  {
    int kr = tid >> 3, c4 = (tid & 7) << 2;
    pb = *reinterpret_cast<const float4*>(&W2[(size_t)kr * 32 + c4]);
  }
  #pragma unroll
  for (int it = 0; it < 4; ++it){
    int li = it * 256 + tid;
    int r = li >> 3, kk = (li & 7) << 2;
    As[r][kk] = pa[it].x; As[r][kk + 1] = pa[it].y;
    As[r][kk + 2] = pa[it].z; As[r][kk + 3] = pa[it].w;
  }
  {
    int kr = tid >> 3, c4 = (tid & 7) << 2;
    Bs[kr][c4] = pb.x; Bs[kr][c4 + 1] = pb.y; Bs[kr][c4 + 2] = pb.z; Bs[kr][c4 + 3] = pb.w;
  }
  __syncthreads();

  for (int k0 = 0; k0 < 256; k0 += 32){
    bool more = (k0 + 32) < 256;
    if (more){
      #pragma unroll
      for (int it = 0; it < 4; ++it){
        int li = it * 256 + tid;
        int r = li >> 3, kk = (li & 7) << 2;
        int row = rowBase + r;
        pa[it] = (row < N) ? *reinterpret_cast<const float4*>(&h1b[(size_t)row * 256 + k0 + 32 + kk])
                           : make_float4(0.f, 0.f, 0.f, 0.f);
      }
      int kr = tid >> 3, c4 = (tid & 7) << 2;
      pb = *reinterpret_cast<const float4*>(&W2[(size_t)(k0 + 32 + kr) * 32 + c4]);
    }
    #pragma unroll
    for (int kk = 0; kk < 32; ++kk){
      float b0 = Bs[kk][tx * 2], b1 = Bs[kk][tx * 2 + 1];
      #pragma unroll
      for (int j = 0; j < 8; ++j){
        float a = As[ty + 16 * j][kk];
        acc[j][0] += a * b0; acc[j][1] += a * b1;
      }
    }
    if (more){
      __syncthreads();
      #pragma unroll
      for (int it = 0; it < 4; ++it){
        int li = it * 256 + tid;
        int r = li >> 3, kk = (li & 7) << 2;
        As[r][kk] = pa[it].x; As[r][kk + 1] = pa[it].y;
        As[r][kk + 2] = pa[it].z; As[r][kk + 3] = pa[it].w;
      }
      int kr = tid >> 3, c4 = (tid & 7) << 2;
      Bs[kr][c4] = pb.x; Bs[kr][c4 + 1] = pb.y; Bs[kr][c4 + 2] = pb.z; Bs[kr][c4 + 3] = pb.w;
      __syncthreads();
    }
  }
  // store h2pre + fused att2 dots
  #pragma unroll
  for (int j = 0; j < 8; ++j){
    int row = rowBase + ty + 16 * j;
    if (row < N)
      *reinterpret_cast<float2*>(&h2pre[(size_t)row * 32 + tx * 2]) =
          make_float2(acc[j][0], acc[j][1]);
  }
  float s0 = att_src2[tx * 2], s1 = att_src2[tx * 2 + 1];
  float d0 = att_dst2[tx * 2], d1 = att_dst2[tx * 2 + 1];
  float ps[8], pd[8];
  #pragma unroll
  for (int j = 0; j < 8; ++j){
    ps[j] = acc[j][0] * s0 + acc[j][1] * s1;
    pd[j] = acc[j][0] * d0 + acc[j][1] * d1;
  }
  #pragma unroll
  for (int st = 8; st > 0; st >>= 1){
    #pragma unroll
    for (int j = 0; j < 8; ++j){
      ps[j] += __shfl_xor(ps[j], st);
      pd[j] += __shfl_xor(pd[j], st);
    }
  }
  if (tx == 0){
    #pragma unroll
    for (int j = 0; j < 8; ++j){
      int row = rowBase + ty + 16 * j;
      if (row < N){
        a_src2[row] = ps[j];
        a_dst2[row] = pd[j];
      }
    }
  }
}

// ---------------- layer 2 node kernel: softmax + aggregate + bias ----------------
__global__ __launch_bounds__(256) void node2_kernel(
    const float* __restrict__ h2pre, const float* __restrict__ a_src2,
    const float* __restrict__ a_dst2, const int* __restrict__ offsets,
    const int* __restrict__ csr_src, const int* __restrict__ csr_eid,
    const float* __restrict__ bias2, float* __restrict__ out_h2,
    float* __restrict__ alpha2_out, int N){
  int gid = blockIdx.x * blockDim.x + threadIdx.x;
  int n = gid >> 6, lane = gid & 63;
  if (n >= N) return;
  int off = offsets[n], deg = offsets[n + 1] - off;
  float adn = a_dst2[n];
  bool have0 = (lane < deg);
  float e0 = -INFINITY;
  if (have0) e0 = lrelu(a_src2[csr_src[off + lane]] + adn);
  float m = e0;
  for (int i = lane + 64; i < deg; i += 64)
    m = fmaxf(m, lrelu(a_src2[csr_src[off + i]] + adn));
  #pragma unroll
  for (int st = 32; st > 0; st >>= 1) m = fmaxf(m, __shfl_xor(m, st));
  float s = have0 ? __expf(e0 - m) : 0.f;
  for (int i = lane + 64; i < deg; i += 64)
    s += __expf(lrelu(a_src2[csr_src[off + i]] + adn) - m);
  #pragma unroll
  for (int st = 32; st > 0; st >>= 1) s += __shfl_xor(s, st);
  float inv = 1.f / (s + EPS_C);
  if (have0) alpha2_out[csr_eid[off + lane]] = __expf(e0 - m) * inv;
  for (int i = lane + 64; i < deg; i += 64){
    int slot = off + i;
    alpha2_out[csr_eid[slot]] = __expf(lrelu(a_src2[csr_src[slot]] + adn) - m) * inv;
  }
  int c = lane & 31, half = lane >> 5;
  float acc = 0.f;
  for (int j = half; j < deg; j += 2){
    int src = csr_src[off + j];
    float al = __expf(lrelu(a_src2[src] + adn) - m) * inv;
    acc += al * h2pre[(size_t)src * 32 + c];
  }
  acc += __shfl_xor(acc, 32);
  if (lane < 32) out_h2[(size_t)n * 32 + c] = acc + bias2[c];
}

// ---------------- echo edge_index (as float) into output regions 1 and 3 ----------------
__global__ void edge_out_kernel(const int* __restrict__ ei, float* __restrict__ out1,
                                float* __restrict__ out3, int n2e){
  int i = blockIdx.x * blockDim.x + threadIdx.x;
  if (i < n2e){
    float v = (float)ei[i];
    out1[i] = v; out3[i] = v;
  }
}

extern "C" void kernel_launch(void* const* d_in, const int* in_sizes, int n_in,
                              void* d_out, int out_size, void* d_ws, size_t ws_size,
                              hipStream_t stream){
  const float* x        = (const float*)d_in[0];
  const int*   ei       = (const int*)d_in[1];
  const float* W1       = (const float*)d_in[2];
  const float* att_src1 = (const float*)d_in[3];
  const float* att_dst1 = (const float*)d_in[4];
  const float* bias1    = (const float*)d_in[5];
  const float* W2       = (const float*)d_in[6];
  const float* att_src2 = (const float*)d_in[7];
  const float* att_dst2 = (const float*)d_in[8];
  const float* bias2    = (const float*)d_in[9];
  float* out = (float*)d_out;
  (void)n_in; (void)out_size; (void)ws_size;

  const int N = in_sizes[0] / 128;
  const int E = in_sizes[1] / 2;
  const int* src = ei;
  const int* dst = ei + E;

  char* ws = (char*)d_ws;
  size_t o = 0;
  auto alloc = [&](size_t bytes) -> void* {
    void* p = ws + o;
    o += (bytes + 255) & ~(size_t)255;
    return p;
  };
  float*  h1      = (float*)alloc((size_t)N * 256 * 4);
  float*  h1b     = (float*)alloc((size_t)N * 256 * 4);
  float*  h2pre   = (float*)alloc((size_t)N * 32 * 4);
  float*  a_src1  = (float*)alloc((size_t)N * 16);
  float*  a_dst1  = (float*)alloc((size_t)N * 16);
  float*  a_src2  = (float*)alloc((size_t)N * 4);
  float*  a_dst2  = (float*)alloc((size_t)N * 4);
  int*    deg     = (int*)alloc((size_t)N * 4);
  int*    offsets = (int*)alloc((size_t)(N + 1) * 4);
  int*    cursor  = (int*)alloc((size_t)N * 4);
  int*    csr_src = (int*)alloc((size_t)E * 4);
  int*    csr_eid = (int*)alloc((size_t)E * 4);

  const size_t OFF1 = (size_t)N * 32;       // edge_index copy 1
  const size_t OFF2 = OFF1 + (size_t)2 * E; // alpha1 [E,4]
  const size_t OFF3 = OFF2 + (size_t)E * 4; // edge_index copy 2
  const size_t OFF4 = OFF3 + (size_t)2 * E; // alpha2 [E]

  // CSR build
  hipLaunchKernelGGL(zero_int_kernel, dim3((N + 255) / 256), dim3(256), 0, stream, deg, N);
  hipLaunchKernelGGL(count_deg_kernel, dim3((E + 255) / 256), dim3(256), 0, stream, dst, deg, E);
  hipLaunchKernelGGL(scan_kernel, dim3(1), dim3(1024), 0, stream, deg, offsets, cursor, N);
  hipLaunchKernelGGL(scatter_kernel, dim3((E + 255) / 256), dim3(256), 0, stream,
                     src, dst, cursor, csr_src, csr_eid, E);
  // layer 1 (attention dots fused into GEMM epilogue)
  hipLaunchKernelGGL(gemm1_kernel, dim3((N + 127) / 128, 4), dim3(256), 0, stream,
                     x, W1, att_src1, att_dst1, h1, a_src1, a_dst1, N);
  hipLaunchKernelGGL(node1_kernel, dim3((N * 64 + 255) / 256), dim3(256), 0, stream,
                     h1, (const float4*)a_src1, (const float*)a_src1, (const float4*)a_dst1,
                     offsets, csr_src, csr_eid, bias1, h1b, out + OFF2, N);
  // layer 2
  hipLaunchKernelGGL(gemm2_kernel, dim3((N + 127) / 128), dim3(256), 0, stream,
                     h1b, W2, att_src2, att_dst2, h2pre, a_src2, a_dst2, N);
  hipLaunchKernelGGL(node2_kernel, dim3((N * 64 + 255) / 256), dim3(256), 0, stream,
                     h2pre, a_src2, a_dst2, offsets, csr_src, csr_eid, bias2,
                     out, out + OFF4, N);
  // edge_index echo
  hipLaunchKernelGGL(edge_out_kernel, dim3((2 * E + 255) / 256), dim3(256), 0, stream,
                     ei, out + OFF1, out + OFF3, 2 * E);
}

// Round 6
// 560.576 us; speedup vs baseline: 1.2234x; 1.0996x over previous
//
#include <hip/hip_runtime.h>
#include <hip/hip_fp16.h>
#include <math.h>

#define NEG_SLOPE 0.2f
#define EPS_C 1e-16f

__device__ __forceinline__ float lrelu(float x){ return x > 0.f ? x : NEG_SLOPE * x; }
__device__ __forceinline__ float eluf(float x){ return x > 0.f ? x : expm1f(x); }

// ---------------- CSR build (by dst) ----------------
__global__ void zero_int_kernel(int* __restrict__ p, int n){
  int i = blockIdx.x * blockDim.x + threadIdx.x;
  if (i < n) p[i] = 0;
}

__global__ void count_deg_kernel(const int* __restrict__ dst, int* __restrict__ deg, int E){
  int i = blockIdx.x * blockDim.x + threadIdx.x;
  if (i < E) atomicAdd(&deg[dst[i]], 1);
}

// one block, 1024 threads: exclusive scan of deg -> offsets, cursor
__global__ void scan_kernel(const int* __restrict__ deg, int* __restrict__ offsets,
                            int* __restrict__ cursor, int N){
  __shared__ int sums[1024];
  int t = threadIdx.x;
  int CH = (N + 1023) >> 10;
  int start = t * CH;
  int end = min(start + CH, N);
  int s = 0;
  for (int i = start; i < end; ++i) s += deg[i];
  sums[t] = s;
  __syncthreads();
  for (int st = 1; st < 1024; st <<= 1){
    int v = (t >= st) ? sums[t - st] : 0;
    __syncthreads();
    sums[t] += v;
    __syncthreads();
  }
  int prefix = (t == 0) ? 0 : sums[t - 1];
  for (int i = start; i < end; ++i){
    offsets[i] = prefix; cursor[i] = prefix; prefix += deg[i];
  }
  if (t == 1023) offsets[N] = sums[1023];
}

__global__ void scatter_kernel(const int* __restrict__ src, const int* __restrict__ dst,
                               int* __restrict__ cursor, int* __restrict__ csr_src,
                               int* __restrict__ csr_eid, int E){
  int i = blockIdx.x * blockDim.x + threadIdx.x;
  if (i < E){
    int d = dst[i];
    int p = atomicAdd(&cursor[d], 1);
    csr_src[p] = src[i];
    csr_eid[p] = i;
  }
}

// ---------------- layer 1 GEMM: h1 = x @ W1  [N,128]x[128,256] ----------------
// 128x64 tile, 8x4 micro-tile, att dots fused in epilogue, K-prefetch pipeline.
// h1 stored as fp16 (read only by node1's edge gather): halves the 800 MB
// logical gather stream. Attention dots stay fp32 (from acc), so alpha is
// unaffected; only the aggregation payload is rounded (~5e-4 rel).
__global__ __launch_bounds__(256) void gemm1_kernel(const float* __restrict__ x,
    const float* __restrict__ W, const float* __restrict__ att_src,
    const float* __restrict__ att_dst, __half* __restrict__ h1,
    float* __restrict__ a_src_f, float* __restrict__ a_dst_f, int N){
  __shared__ float As[128][33];
  __shared__ float Bs[32][65];
  int tid = threadIdx.x;
  int tx = tid & 15, ty = tid >> 4;
  int rowBase = blockIdx.x * 128;
  int head = blockIdx.y;          // col block == head
  int colBase = head * 64;
  float acc[8][4] = {};
  float4 pa[4], pb[2];

  // load chunk 0 into regs
  #pragma unroll
  for (int it = 0; it < 4; ++it){
    int li = it * 256 + tid;
    int r = li >> 3, kk = (li & 7) << 2;
    int row = rowBase + r;
    pa[it] = (row < N) ? *reinterpret_cast<const float4*>(&x[(size_t)row * 128 + kk])
                       : make_float4(0.f, 0.f, 0.f, 0.f);
  }
  #pragma unroll
  for (int it = 0; it < 2; ++it){
    int li = it * 256 + tid;
    int kr = li >> 4, c4 = (li & 15) << 2;
    pb[it] = *reinterpret_cast<const float4*>(&W[(size_t)kr * 256 + colBase + c4]);
  }
  #pragma unroll
  for (int it = 0; it < 4; ++it){
    int li = it * 256 + tid;
    int r = li >> 3, kk = (li & 7) << 2;
    As[r][kk] = pa[it].x; As[r][kk + 1] = pa[it].y;
    As[r][kk + 2] = pa[it].z; As[r][kk + 3] = pa[it].w;
  }
  #pragma unroll
  for (int it = 0; it < 2; ++it){
    int li = it * 256 + tid;
    int kr = li >> 4, c4 = (li & 15) << 2;
    Bs[kr][c4] = pb[it].x; Bs[kr][c4 + 1] = pb[it].y;
    Bs[kr][c4 + 2] = pb[it].z; Bs[kr][c4 + 3] = pb[it].w;
  }
  __syncthreads();

  for (int k0 = 0; k0 < 128; k0 += 32){
    bool more = (k0 + 32) < 128;
    if (more){
      #pragma unroll
      for (int it = 0; it < 4; ++it){
        int li = it * 256 + tid;
        int r = li >> 3, kk = (li & 7) << 2;
        int row = rowBase + r;
        pa[it] = (row < N) ? *reinterpret_cast<const float4*>(&x[(size_t)row * 128 + k0 + 32 + kk])
                           : make_float4(0.f, 0.f, 0.f, 0.f);
      }
      #pragma unroll
      for (int it = 0; it < 2; ++it){
        int li = it * 256 + tid;
        int kr = li >> 4, c4 = (li & 15) << 2;
        pb[it] = *reinterpret_cast<const float4*>(&W[(size_t)(k0 + 32 + kr) * 256 + colBase + c4]);
      }
    }
    #pragma unroll
    for (int kk = 0; kk < 32; ++kk){
      float4 b = make_float4(Bs[kk][tx * 4], Bs[kk][tx * 4 + 1],
                             Bs[kk][tx * 4 + 2], Bs[kk][tx * 4 + 3]);
      #pragma unroll
      for (int j = 0; j < 8; ++j){
        float a = As[ty + 16 * j][kk];
        acc[j][0] += a * b.x; acc[j][1] += a * b.y;
        acc[j][2] += a * b.z; acc[j][3] += a * b.w;
      }
    }
    if (more){
      __syncthreads();
      #pragma unroll
      for (int it = 0; it < 4; ++it){
        int li = it * 256 + tid;
        int r = li >> 3, kk = (li & 7) << 2;
        As[r][kk] = pa[it].x; As[r][kk + 1] = pa[it].y;
        As[r][kk + 2] = pa[it].z; As[r][kk + 3] = pa[it].w;
      }
      #pragma unroll
      for (int it = 0; it < 2; ++it){
        int li = it * 256 + tid;
        int kr = li >> 4, c4 = (li & 15) << 2;
        Bs[kr][c4] = pb[it].x; Bs[kr][c4 + 1] = pb[it].y;
        Bs[kr][c4 + 2] = pb[it].z; Bs[kr][c4 + 3] = pb[it].w;
      }
      __syncthreads();
    }
  }
  // store h1 tile as fp16 (8 B per thread per j)
  #pragma unroll
  for (int j = 0; j < 8; ++j){
    int row = rowBase + ty + 16 * j;
    if (row < N){
      __half2 v01 = __floats2half2_rn(acc[j][0], acc[j][1]);
      __half2 v23 = __floats2half2_rn(acc[j][2], acc[j][3]);
      float2 pack;
      pack.x = *reinterpret_cast<float*>(&v01);
      pack.y = *reinterpret_cast<float*>(&v23);
      *reinterpret_cast<float2*>(&h1[(size_t)row * 256 + colBase + tx * 4]) = pack;
    }
  }
  // fused attention dots for this head (fp32 acc -> alpha unaffected)
  float4 s4 = *reinterpret_cast<const float4*>(&att_src[colBase + tx * 4]);
  float4 d4 = *reinterpret_cast<const float4*>(&att_dst[colBase + tx * 4]);
  float ps[8], pd[8];
  #pragma unroll
  for (int j = 0; j < 8; ++j){
    ps[j] = acc[j][0] * s4.x + acc[j][1] * s4.y + acc[j][2] * s4.z + acc[j][3] * s4.w;
    pd[j] = acc[j][0] * d4.x + acc[j][1] * d4.y + acc[j][2] * d4.z + acc[j][3] * d4.w;
  }
  #pragma unroll
  for (int st = 8; st > 0; st >>= 1){
    #pragma unroll
    for (int j = 0; j < 8; ++j){
      ps[j] += __shfl_xor(ps[j], st);
      pd[j] += __shfl_xor(pd[j], st);
    }
  }
  if (tx == 0){
    #pragma unroll
    for (int j = 0; j < 8; ++j){
      int row = rowBase + ty + 16 * j;
      if (row < N){
        a_src_f[(size_t)row * 4 + head] = ps[j];
        a_dst_f[(size_t)row * 4 + head] = pd[j];
      }
    }
  }
}

// ---------------- layer 1 node kernel: softmax + aggregate + bias + ELU ----------------
__global__ __launch_bounds__(256) void node1_kernel(
    const __half* __restrict__ h1, const float4* __restrict__ a_src,
    const float* __restrict__ a_src_f, const float4* __restrict__ a_dst,
    const int* __restrict__ offsets, const int* __restrict__ csr_src,
    const int* __restrict__ csr_eid, const float* __restrict__ bias,
    float* __restrict__ h1b, float* __restrict__ alpha1_out, int N){
  int gid = blockIdx.x * blockDim.x + threadIdx.x;
  int n = gid >> 6, lane = gid & 63;
  if (n >= N) return;
  int off = offsets[n];
  int deg = offsets[n + 1] - off;
  float4 ad = a_dst[n];
  // pass 1: max (cache slot-0 logits)
  bool have0 = (lane < deg);
  float4 e0 = make_float4(-INFINITY, -INFINITY, -INFINITY, -INFINITY);
  if (have0){
    float4 as = a_src[csr_src[off + lane]];
    e0 = make_float4(lrelu(as.x + ad.x), lrelu(as.y + ad.y),
                     lrelu(as.z + ad.z), lrelu(as.w + ad.w));
  }
  float m0 = e0.x, m1 = e0.y, m2 = e0.z, m3 = e0.w;
  for (int i = lane + 64; i < deg; i += 64){
    float4 as = a_src[csr_src[off + i]];
    m0 = fmaxf(m0, lrelu(as.x + ad.x));
    m1 = fmaxf(m1, lrelu(as.y + ad.y));
    m2 = fmaxf(m2, lrelu(as.z + ad.z));
    m3 = fmaxf(m3, lrelu(as.w + ad.w));
  }
  #pragma unroll
  for (int st = 32; st > 0; st >>= 1){
    m0 = fmaxf(m0, __shfl_xor(m0, st));
    m1 = fmaxf(m1, __shfl_xor(m1, st));
    m2 = fmaxf(m2, __shfl_xor(m2, st));
    m3 = fmaxf(m3, __shfl_xor(m3, st));
  }
  // pass 2: sum (slot 0 from cache)
  float s0 = 0.f, s1 = 0.f, s2 = 0.f, s3 = 0.f;
  if (have0){
    s0 = __expf(e0.x - m0); s1 = __expf(e0.y - m1);
    s2 = __expf(e0.z - m2); s3 = __expf(e0.w - m3);
  }
  for (int i = lane + 64; i < deg; i += 64){
    float4 as = a_src[csr_src[off + i]];
    s0 += __expf(lrelu(as.x + ad.x) - m0);
    s1 += __expf(lrelu(as.y + ad.y) - m1);
    s2 += __expf(lrelu(as.z + ad.z) - m2);
    s3 += __expf(lrelu(as.w + ad.w) - m3);
  }
  #pragma unroll
  for (int st = 32; st > 0; st >>= 1){
    s0 += __shfl_xor(s0, st); s1 += __shfl_xor(s1, st);
    s2 += __shfl_xor(s2, st); s3 += __shfl_xor(s3, st);
  }
  float i0 = 1.f / (s0 + EPS_C), i1 = 1.f / (s1 + EPS_C);
  float i2 = 1.f / (s2 + EPS_C), i3 = 1.f / (s3 + EPS_C);
  // pass 3: alpha write in original edge order (slot 0 from cache)
  if (have0){
    int eid = csr_eid[off + lane];
    *reinterpret_cast<float4*>(&alpha1_out[(size_t)eid * 4]) =
        make_float4(__expf(e0.x - m0) * i0, __expf(e0.y - m1) * i1,
                    __expf(e0.z - m2) * i2, __expf(e0.w - m3) * i3);
  }
  for (int i = lane + 64; i < deg; i += 64){
    int slot = off + i;
    float4 as = a_src[csr_src[slot]];
    int eid = csr_eid[slot];
    *reinterpret_cast<float4*>(&alpha1_out[(size_t)eid * 4]) =
        make_float4(__expf(lrelu(as.x + ad.x) - m0) * i0,
                    __expf(lrelu(as.y + ad.y) - m1) * i1,
                    __expf(lrelu(as.z + ad.z) - m2) * i2,
                    __expf(lrelu(as.w + ad.w) - m3) * i3);
  }
  // aggregation: lane owns channels [4*lane, 4*lane+3]; head = lane>>4.
  // fp16 gather (8 B/lane/edge), fp32 accumulate.
  int head = lane >> 4;
  float mh  = head == 0 ? m0 : head == 1 ? m1 : head == 2 ? m2 : m3;
  float ih  = head == 0 ? i0 : head == 1 ? i1 : head == 2 ? i2 : i3;
  float adh = head == 0 ? ad.x : head == 1 ? ad.y : head == 2 ? ad.z : ad.w;
  float4 accA = make_float4(0.f, 0.f, 0.f, 0.f);
  float4 accB = make_float4(0.f, 0.f, 0.f, 0.f);
  float4 accC = make_float4(0.f, 0.f, 0.f, 0.f);
  float4 accD = make_float4(0.f, 0.f, 0.f, 0.f);
  int j = 0;
  for (; j + 3 < deg; j += 4){
    int sA = csr_src[off + j];
    int sB = csr_src[off + j + 1];
    int sC = csr_src[off + j + 2];
    int sD = csr_src[off + j + 3];
    float alA = __expf(lrelu(a_src_f[(size_t)sA * 4 + head] + adh) - mh) * ih;
    float alB = __expf(lrelu(a_src_f[(size_t)sB * 4 + head] + adh) - mh) * ih;
    float alC = __expf(lrelu(a_src_f[(size_t)sC * 4 + head] + adh) - mh) * ih;
    float alD = __expf(lrelu(a_src_f[(size_t)sD * 4 + head] + adh) - mh) * ih;
    float2 rA = *reinterpret_cast<const float2*>(&h1[(size_t)sA * 256 + lane * 4]);
    float2 rB = *reinterpret_cast<const float2*>(&h1[(size_t)sB * 256 + lane * 4]);
    float2 rC = *reinterpret_cast<const float2*>(&h1[(size_t)sC * 256 + lane * 4]);
    float2 rD = *reinterpret_cast<const float2*>(&h1[(size_t)sD * 256 + lane * 4]);
    float2 fA0 = __half22float2(*reinterpret_cast<__half2*>(&rA.x));
    float2 fA1 = __half22float2(*reinterpret_cast<__half2*>(&rA.y));
    float2 fB0 = __half22float2(*reinterpret_cast<__half2*>(&rB.x));
    float2 fB1 = __half22float2(*reinterpret_cast<__half2*>(&rB.y));
    float2 fC0 = __half22float2(*reinterpret_cast<__half2*>(&rC.x));
    float2 fC1 = __half22float2(*reinterpret_cast<__half2*>(&rC.y));
    float2 fD0 = __half22float2(*reinterpret_cast<__half2*>(&rD.x));
    float2 fD1 = __half22float2(*reinterpret_cast<__half2*>(&rD.y));
    accA.x += alA * fA0.x; accA.y += alA * fA0.y; accA.z += alA * fA1.x; accA.w += alA * fA1.y;
    accB.x += alB * fB0.x; accB.y += alB * fB0.y; accB.z += alB * fB1.x; accB.w += alB * fB1.y;
    accC.x += alC * fC0.x; accC.y += alC * fC0.y; accC.z += alC * fC1.x; accC.w += alC * fC1.y;
    accD.x += alD * fD0.x; accD.y += alD * fD0.y; accD.z += alD * fD1.x; accD.w += alD * fD1.y;
  }
  for (; j < deg; ++j){
    int sA = csr_src[off + j];
    float alA = __expf(lrelu(a_src_f[(size_t)sA * 4 + head] + adh) - mh) * ih;
    float2 rA = *reinterpret_cast<const float2*>(&h1[(size_t)sA * 256 + lane * 4]);
    float2 fA0 = __half22float2(*reinterpret_cast<__half2*>(&rA.x));
    float2 fA1 = __half22float2(*reinterpret_cast<__half2*>(&rA.y));
    accA.x += alA * fA0.x; accA.y += alA * fA0.y; accA.z += alA * fA1.x; accA.w += alA * fA1.y;
  }
  accA.x += accB.x + accC.x + accD.x;
  accA.y += accB.y + accC.y + accD.y;
  accA.z += accB.z + accC.z + accD.z;
  accA.w += accB.w + accC.w + accD.w;
  float4 b = *reinterpret_cast<const float4*>(&bias[lane * 4]);
  float4 o = make_float4(eluf(accA.x + b.x), eluf(accA.y + b.y),
                         eluf(accA.z + b.z), eluf(accA.w + b.w));
  *reinterpret_cast<float4*>(&h1b[(size_t)n * 256 + lane * 4]) = o;
}

// ---------------- layer 2 GEMM: h2pre = h1b @ W2 [N,256]x[256,32] ----------------
__global__ __launch_bounds__(256) void gemm2_kernel(const float* __restrict__ h1b,
    const float* __restrict__ W2, const float* __restrict__ att_src2,
    const float* __restrict__ att_dst2, float* __restrict__ h2pre,
    float* __restrict__ a_src2, float* __restrict__ a_dst2, int N){
  __shared__ float As[128][33];
  __shared__ float Bs[32][33];
  int tid = threadIdx.x;
  int tx = tid & 15, ty = tid >> 4;
  int rowBase = blockIdx.x * 128;
  float acc[8][2] = {};
  float4 pa[4], pb;

  #pragma unroll
  for (int it = 0; it < 4; ++it){
    int li = it * 256 + tid;
    int r = li >> 3, kk = (li & 7) << 2;
    int row = rowBase + r;
    pa[it] = (row < N) ? *reinterpret_cast<const float4*>(&h1b[(size_t)row * 256 + kk])
                       : make_float4(0.f, 0.f, 0.f, 0.f);
  }
  {
    int kr = tid >> 3, c4 = (tid & 7) << 2;
    pb = *reinterpret_cast<const float4*>(&W2[(size_t)kr * 32 + c4]);
  }
  #pragma unroll
  for (int it = 0; it < 4; ++it){
    int li = it * 256 + tid;
    int r = li >> 3, kk = (li & 7) << 2;
    As[r][kk] = pa[it].x; As[r][kk + 1] = pa[it].y;
    As[r][kk + 2] = pa[it].z; As[r][kk + 3] = pa[it].w;
  }
  {
    int kr = tid >> 3, c4 = (tid & 7) << 2;
    Bs[kr][c4] = pb.x; Bs[kr][c4 + 1] = pb.y; Bs[kr][c4 + 2] = pb.z; Bs[kr][c4 + 3] = pb.w;
  }
  __syncthreads();

  for (int k0 = 0; k0 < 256; k0 += 32){
    bool more = (k0 + 32) < 256;
    if (more){
      #pragma unroll
      for (int it = 0; it < 4; ++it){
        int li = it * 256 + tid;
        int r = li >> 3, kk = (li & 7) << 2;
        int row = rowBase + r;
        pa[it] = (row < N) ? *reinterpret_cast<const float4*>(&h1b[(size_t)row * 256 + k0 + 32 + kk])
                           : make_float4(0.f, 0.f, 0.f, 0.f);
      }
      int kr = tid >> 3, c4 = (tid & 7) << 2;
      pb = *reinterpret_cast<const float4*>(&W2[(size_t)(k0 + 32 + kr) * 32 + c4]);
    }
    #pragma unroll
    for (int kk = 0; kk < 32; ++kk){
      float b0 = Bs[kk][tx * 2], b1 = Bs[kk][tx * 2 + 1];
      #pragma unroll
      for (int j = 0; j < 8; ++j){
        float a = As[ty + 16 * j][kk];
        acc[j][0] += a * b0; acc[j][1] += a * b1;
      }
    }
    if (more){
      __syncthreads();
      #pragma unroll
      for (int it = 0; it < 4; ++it){
        int li = it * 256 + tid;
        int r = li >> 3, kk = (li & 7) << 2;
        As[r][kk] = pa[it].x; As[r][kk + 1] = pa[it].y;
        As[r][kk + 2] = pa[it].z; As[r][kk + 3] = pa[it].w;
      }
      int kr = tid >> 3, c4 = (tid & 7) << 2;
      Bs[kr][c4] = pb.x; Bs[kr][c4 + 1] = pb.y; Bs[kr][c4 + 2] = pb.z; Bs[kr][c4 + 3] = pb.w;
      __syncthreads();
    }
  }
  #pragma unroll
  for (int j = 0; j < 8; ++j){
    int row = rowBase + ty + 16 * j;
    if (row < N)
      *reinterpret_cast<float2*>(&h2pre[(size_t)row * 32 + tx * 2]) =
          make_float2(acc[j][0], acc[j][1]);
  }
  float s0 = att_src2[tx * 2], s1 = att_src2[tx * 2 + 1];
  float d0 = att_dst2[tx * 2], d1 = att_dst2[tx * 2 + 1];
  float ps[8], pd[8];
  #pragma unroll
  for (int j = 0; j < 8; ++j){
    ps[j] = acc[j][0] * s0 + acc[j][1] * s1;
    pd[j] = acc[j][0] * d0 + acc[j][1] * d1;
  }
  #pragma unroll
  for (int st = 8; st > 0; st >>= 1){
    #pragma unroll
    for (int j = 0; j < 8; ++j){
      ps[j] += __shfl_xor(ps[j], st);
      pd[j] += __shfl_xor(pd[j], st);
    }
  }
  if (tx == 0){
    #pragma unroll
    for (int j = 0; j < 8; ++j){
      int row = rowBase + ty + 16 * j;
      if (row < N){
        a_src2[row] = ps[j];
        a_dst2[row] = pd[j];
      }
    }
  }
}

// ---------------- layer 2 node kernel: softmax + aggregate + bias ----------------
__global__ __launch_bounds__(256) void node2_kernel(
    const float* __restrict__ h2pre, const float* __restrict__ a_src2,
    const float* __restrict__ a_dst2, const int* __restrict__ offsets,
    const int* __restrict__ csr_src, const int* __restrict__ csr_eid,
    const float* __restrict__ bias2, float* __restrict__ out_h2,
    float* __restrict__ alpha2_out, int N){
  int gid = blockIdx.x * blockDim.x + threadIdx.x;
  int n = gid >> 6, lane = gid & 63;
  if (n >= N) return;
  int off = offsets[n], deg = offsets[n + 1] - off;
  float adn = a_dst2[n];
  bool have0 = (lane < deg);
  float e0 = -INFINITY;
  if (have0) e0 = lrelu(a_src2[csr_src[off + lane]] + adn);
  float m = e0;
  for (int i = lane + 64; i < deg; i += 64)
    m = fmaxf(m, lrelu(a_src2[csr_src[off + i]] + adn));
  #pragma unroll
  for (int st = 32; st > 0; st >>= 1) m = fmaxf(m, __shfl_xor(m, st));
  float s = have0 ? __expf(e0 - m) : 0.f;
  for (int i = lane + 64; i < deg; i += 64)
    s += __expf(lrelu(a_src2[csr_src[off + i]] + adn) - m);
  #pragma unroll
  for (int st = 32; st > 0; st >>= 1) s += __shfl_xor(s, st);
  float inv = 1.f / (s + EPS_C);
  if (have0) alpha2_out[csr_eid[off + lane]] = __expf(e0 - m) * inv;
  for (int i = lane + 64; i < deg; i += 64){
    int slot = off + i;
    alpha2_out[csr_eid[slot]] = __expf(lrelu(a_src2[csr_src[slot]] + adn) - m) * inv;
  }
  int c = lane & 31, half = lane >> 5;
  float acc = 0.f;
  for (int j = half; j < deg; j += 2){
    int src = csr_src[off + j];
    float al = __expf(lrelu(a_src2[src] + adn) - m) * inv;
    acc += al * h2pre[(size_t)src * 32 + c];
  }
  acc += __shfl_xor(acc, 32);
  if (lane < 32) out_h2[(size_t)n * 32 + c] = acc + bias2[c];
}

// ---------------- echo edge_index (as float) into output regions 1 and 3 ----------------
__global__ void edge_out_kernel(const int* __restrict__ ei, float* __restrict__ out1,
                                float* __restrict__ out3, int n2e){
  int i = blockIdx.x * blockDim.x + threadIdx.x;
  if (i < n2e){
    float v = (float)ei[i];
    out1[i] = v; out3[i] = v;
  }
}

extern "C" void kernel_launch(void* const* d_in, const int* in_sizes, int n_in,
                              void* d_out, int out_size, void* d_ws, size_t ws_size,
                              hipStream_t stream){
  const float* x        = (const float*)d_in[0];
  const int*   ei       = (const int*)d_in[1];
  const float* W1       = (const float*)d_in[2];
  const float* att_src1 = (const float*)d_in[3];
  const float* att_dst1 = (const float*)d_in[4];
  const float* bias1    = (const float*)d_in[5];
  const float* W2       = (const float*)d_in[6];
  const float* att_src2 = (const float*)d_in[7];
  const float* att_dst2 = (const float*)d_in[8];
  const float* bias2    = (const float*)d_in[9];
  float* out = (float*)d_out;
  (void)n_in; (void)out_size; (void)ws_size;

  const int N = in_sizes[0] / 128;
  const int E = in_sizes[1] / 2;
  const int* src = ei;
  const int* dst = ei + E;

  char* ws = (char*)d_ws;
  size_t o = 0;
  auto alloc = [&](size_t bytes) -> void* {
    void* p = ws + o;
    o += (bytes + 255) & ~(size_t)255;
    return p;
  };
  __half* h1      = (__half*)alloc((size_t)N * 256 * 2);   // fp16 gather payload
  float*  h1b     = (float*)alloc((size_t)N * 256 * 4);
  float*  h2pre   = (float*)alloc((size_t)N * 32 * 4);
  float*  a_src1  = (float*)alloc((size_t)N * 16);
  float*  a_dst1  = (float*)alloc((size_t)N * 16);
  float*  a_src2  = (float*)alloc((size_t)N * 4);
  float*  a_dst2  = (float*)alloc((size_t)N * 4);
  int*    deg     = (int*)alloc((size_t)N * 4);
  int*    offsets = (int*)alloc((size_t)(N + 1) * 4);
  int*    cursor  = (int*)alloc((size_t)N * 4);
  int*    csr_src = (int*)alloc((size_t)E * 4);
  int*    csr_eid = (int*)alloc((size_t)E * 4);

  const size_t OFF1 = (size_t)N * 32;       // edge_index copy 1
  const size_t OFF2 = OFF1 + (size_t)2 * E; // alpha1 [E,4]
  const size_t OFF3 = OFF2 + (size_t)E * 4; // edge_index copy 2
  const size_t OFF4 = OFF3 + (size_t)2 * E; // alpha2 [E]

  // CSR build
  hipLaunchKernelGGL(zero_int_kernel, dim3((N + 255) / 256), dim3(256), 0, stream, deg, N);
  hipLaunchKernelGGL(count_deg_kernel, dim3((E + 255) / 256), dim3(256), 0, stream, dst, deg, E);
  hipLaunchKernelGGL(scan_kernel, dim3(1), dim3(1024), 0, stream, deg, offsets, cursor, N);
  hipLaunchKernelGGL(scatter_kernel, dim3((E + 255) / 256), dim3(256), 0, stream,
                     src, dst, cursor, csr_src, csr_eid, E);
  // layer 1 (attention dots fused into GEMM epilogue)
  hipLaunchKernelGGL(gemm1_kernel, dim3((N + 127) / 128, 4), dim3(256), 0, stream,
                     x, W1, att_src1, att_dst1, h1, a_src1, a_dst1, N);
  hipLaunchKernelGGL(node1_kernel, dim3((N * 64 + 255) / 256), dim3(256), 0, stream,
                     h1, (const float4*)a_src1, (const float*)a_src1, (const float4*)a_dst1,
                     offsets, csr_src, csr_eid, bias1, h1b, out + OFF2, N);
  // layer 2
  hipLaunchKernelGGL(gemm2_kernel, dim3((N + 127) / 128), dim3(256), 0, stream,
                     h1b, W2, att_src2, att_dst2, h2pre, a_src2, a_dst2, N);
  hipLaunchKernelGGL(node2_kernel, dim3((N * 64 + 255) / 256), dim3(256), 0, stream,
                     h2pre, a_src2, a_dst2, offsets, csr_src, csr_eid, bias2,
                     out, out + OFF4, N);
  // edge_index echo
  hipLaunchKernelGGL(edge_out_kernel, dim3((2 * E + 255) / 256), dim3(256), 0, stream,
                     ei, out + OFF1, out + OFF3, 2 * E);
}

// Round 7
// 487.705 us; speedup vs baseline: 1.4062x; 1.1494x over previous
//
#include <hip/hip_runtime.h>
#include <hip/hip_fp16.h>
#include <math.h>

#define NEG_SLOPE 0.2f
#define EPS_C 1e-16f

typedef _Float16 f16x8 __attribute__((ext_vector_type(8)));
typedef float f32x4 __attribute__((ext_vector_type(4)));

__device__ __forceinline__ float lrelu(float x){ return x > 0.f ? x : NEG_SLOPE * x; }
__device__ __forceinline__ float eluf(float x){ return x > 0.f ? x : expm1f(x); }

// ---------------- CSR build (by dst) ----------------
__global__ void zero_int_kernel(int* __restrict__ p, int n){
  int i = blockIdx.x * blockDim.x + threadIdx.x;
  if (i < n) p[i] = 0;
}

__global__ void count_deg_kernel(const int* __restrict__ dst, int* __restrict__ deg, int E){
  int i = blockIdx.x * blockDim.x + threadIdx.x;
  if (i < E) atomicAdd(&deg[dst[i]], 1);
}

// one block, 1024 threads: exclusive scan of deg -> offsets, cursor
__global__ void scan_kernel(const int* __restrict__ deg, int* __restrict__ offsets,
                            int* __restrict__ cursor, int N){
  __shared__ int sums[1024];
  int t = threadIdx.x;
  int CH = (N + 1023) >> 10;
  int start = t * CH;
  int end = min(start + CH, N);
  int s = 0;
  for (int i = start; i < end; ++i) s += deg[i];
  sums[t] = s;
  __syncthreads();
  for (int st = 1; st < 1024; st <<= 1){
    int v = (t >= st) ? sums[t - st] : 0;
    __syncthreads();
    sums[t] += v;
    __syncthreads();
  }
  int prefix = (t == 0) ? 0 : sums[t - 1];
  for (int i = start; i < end; ++i){
    offsets[i] = prefix; cursor[i] = prefix; prefix += deg[i];
  }
  if (t == 1023) offsets[N] = sums[1023];
}

__global__ void scatter_kernel(const int* __restrict__ src, const int* __restrict__ dst,
                               int* __restrict__ cursor, int* __restrict__ csr_src,
                               int* __restrict__ csr_eid, int E){
  int i = blockIdx.x * blockDim.x + threadIdx.x;
  if (i < E){
    int d = dst[i];
    int p = atomicAdd(&cursor[d], 1);
    csr_src[p] = src[i];
    csr_eid[p] = i;
  }
}

// ---------------- input converts: x -> fp16, W1 -> fp16 transposed ----------------
__global__ void cvt_x_kernel(const float* __restrict__ x, __half* __restrict__ x16, int n4){
  int i = blockIdx.x * blockDim.x + threadIdx.x;
  if (i < n4){
    float4 v = *reinterpret_cast<const float4*>(&x[(size_t)i * 4]);
    __half2 h01 = __floats2half2_rn(v.x, v.y);
    __half2 h23 = __floats2half2_rn(v.z, v.w);
    uint2 pack;
    pack.x = *reinterpret_cast<unsigned int*>(&h01);
    pack.y = *reinterpret_cast<unsigned int*>(&h23);
    *reinterpret_cast<uint2*>(&x16[(size_t)i * 4]) = pack;
  }
}

// W1 [128][256] fp32 -> W1t [256][128] fp16 (coalesced reads, scattered 2B writes; 32K elems)
__global__ void cvt_w1_kernel(const float* __restrict__ W1, __half* __restrict__ W1t){
  int i = blockIdx.x * blockDim.x + threadIdx.x;   // 32768 threads
  int k = i >> 8, c = i & 255;
  if (i < 128 * 256) W1t[(size_t)c * 128 + k] = __float2half(W1[(size_t)k * 256 + c]);
}

// ---------------- layer 1 GEMM via MFMA: h1 = x16 @ W1t  [N,128]x[128,256] ----
// R6 counters: fp32 vector GEMM stuck at 117us, VALUBusy 25%, 75% stall.
// MFMA f16 (fp32 accum) makes compute ~free; K=128 staged whole in LDS
// (no K-loop). Per wave: 32x64 out = 2x4 frags x 4 K-steps = 32 MFMA.
// LDS rows padded to 136 halves -> 2-way bank alias on frag reads (free).
// Attention dots fused in epilogue from fp32 acc.
__global__ __launch_bounds__(256) void gemm1_kernel(const __half* __restrict__ x16,
    const __half* __restrict__ W1t, const float* __restrict__ att_src,
    const float* __restrict__ att_dst, __half* __restrict__ h1,
    float* __restrict__ a_src_f, float* __restrict__ a_dst_f, int N){
  __shared__ _Float16 As[128 * 136];   // x tile [row][k]
  __shared__ _Float16 Bs[64 * 136];    // W1t tile [col][k]
  int tid = threadIdx.x;
  int lane = tid & 63, wid = tid >> 6;
  int rowBase = blockIdx.x * 128;
  int head = blockIdx.y;
  int colBase = head * 64;

  // stage x16 tile: 128 rows x 128 halves, 16B per (it,thread)
  #pragma unroll
  for (int it = 0; it < 8; ++it){
    int li = it * 256 + tid;
    int r = li >> 4, seg = li & 15;
    int grow = rowBase + r;
    f16x8 v = {};
    if (grow < N) v = *reinterpret_cast<const f16x8*>(&x16[(size_t)grow * 128 + seg * 8]);
    *reinterpret_cast<f16x8*>(&As[r * 136 + seg * 8]) = v;
  }
  // stage W1t tile: 64 cols x 128 halves
  #pragma unroll
  for (int it = 0; it < 4; ++it){
    int li = it * 256 + tid;
    int c = li >> 4, seg = li & 15;
    f16x8 v = *reinterpret_cast<const f16x8*>(&W1t[(size_t)(colBase + c) * 128 + seg * 8]);
    *reinterpret_cast<f16x8*>(&Bs[c * 136 + seg * 8]) = v;
  }
  __syncthreads();

  // wave wid owns rows [wid*32, wid*32+32), all 64 cols
  f32x4 acc[2][4] = {};
  int l15 = lane & 15, l4 = lane >> 4;
  #pragma unroll
  for (int ks = 0; ks < 4; ++ks){
    int kOff = ks * 32 + l4 * 8;
    f16x8 a0 = *reinterpret_cast<const f16x8*>(&As[(wid * 32 + l15) * 136 + kOff]);
    f16x8 a1 = *reinterpret_cast<const f16x8*>(&As[(wid * 32 + 16 + l15) * 136 + kOff]);
    #pragma unroll
    for (int cc = 0; cc < 4; ++cc){
      f16x8 b = *reinterpret_cast<const f16x8*>(&Bs[(cc * 16 + l15) * 136 + kOff]);
      acc[0][cc] = __builtin_amdgcn_mfma_f32_16x16x32_f16(a0, b, acc[0][cc], 0, 0, 0);
      acc[1][cc] = __builtin_amdgcn_mfma_f32_16x16x32_f16(a1, b, acc[1][cc], 0, 0, 0);
    }
  }

  // store h1 (fp16). C/D layout: col = lane&15, row = (lane>>4)*4 + reg.
  #pragma unroll
  for (int rr = 0; rr < 2; ++rr){
    #pragma unroll
    for (int i = 0; i < 4; ++i){
      int row = rowBase + wid * 32 + rr * 16 + l4 * 4 + i;
      if (row < N){
        #pragma unroll
        for (int cc = 0; cc < 4; ++cc)
          h1[(size_t)row * 256 + colBase + cc * 16 + l15] = __float2half(acc[rr][cc][i]);
      }
    }
  }
  // fused attention dots (per-row reduce over 64 cols; 16-lane butterfly)
  float sw[4], dw[4];
  #pragma unroll
  for (int cc = 0; cc < 4; ++cc){
    sw[cc] = att_src[colBase + cc * 16 + l15];
    dw[cc] = att_dst[colBase + cc * 16 + l15];
  }
  #pragma unroll
  for (int rr = 0; rr < 2; ++rr){
    #pragma unroll
    for (int i = 0; i < 4; ++i){
      float ts = 0.f, td = 0.f;
      #pragma unroll
      for (int cc = 0; cc < 4; ++cc){
        ts += acc[rr][cc][i] * sw[cc];
        td += acc[rr][cc][i] * dw[cc];
      }
      #pragma unroll
      for (int st = 8; st > 0; st >>= 1){
        ts += __shfl_xor(ts, st);
        td += __shfl_xor(td, st);
      }
      int row = rowBase + wid * 32 + rr * 16 + l4 * 4 + i;
      if (l15 == 0 && row < N){
        a_src_f[(size_t)row * 4 + head] = ts;
        a_dst_f[(size_t)row * 4 + head] = td;
      }
    }
  }
}

// ---------------- layer 1 node kernel: softmax + aggregate + bias + ELU ----------------
__global__ __launch_bounds__(256) void node1_kernel(
    const __half* __restrict__ h1, const float4* __restrict__ a_src,
    const float* __restrict__ a_src_f, const float4* __restrict__ a_dst,
    const int* __restrict__ offsets, const int* __restrict__ csr_src,
    const int* __restrict__ csr_eid, const float* __restrict__ bias,
    float* __restrict__ h1b, float* __restrict__ alpha1_out, int N){
  int gid = blockIdx.x * blockDim.x + threadIdx.x;
  int n = gid >> 6, lane = gid & 63;
  if (n >= N) return;
  int off = offsets[n];
  int deg = offsets[n + 1] - off;
  float4 ad = a_dst[n];
  bool have0 = (lane < deg);
  float4 e0 = make_float4(-INFINITY, -INFINITY, -INFINITY, -INFINITY);
  if (have0){
    float4 as = a_src[csr_src[off + lane]];
    e0 = make_float4(lrelu(as.x + ad.x), lrelu(as.y + ad.y),
                     lrelu(as.z + ad.z), lrelu(as.w + ad.w));
  }
  float m0 = e0.x, m1 = e0.y, m2 = e0.z, m3 = e0.w;
  for (int i = lane + 64; i < deg; i += 64){
    float4 as = a_src[csr_src[off + i]];
    m0 = fmaxf(m0, lrelu(as.x + ad.x));
    m1 = fmaxf(m1, lrelu(as.y + ad.y));
    m2 = fmaxf(m2, lrelu(as.z + ad.z));
    m3 = fmaxf(m3, lrelu(as.w + ad.w));
  }
  #pragma unroll
  for (int st = 32; st > 0; st >>= 1){
    m0 = fmaxf(m0, __shfl_xor(m0, st));
    m1 = fmaxf(m1, __shfl_xor(m1, st));
    m2 = fmaxf(m2, __shfl_xor(m2, st));
    m3 = fmaxf(m3, __shfl_xor(m3, st));
  }
  float s0 = 0.f, s1 = 0.f, s2 = 0.f, s3 = 0.f;
  if (have0){
    s0 = __expf(e0.x - m0); s1 = __expf(e0.y - m1);
    s2 = __expf(e0.z - m2); s3 = __expf(e0.w - m3);
  }
  for (int i = lane + 64; i < deg; i += 64){
    float4 as = a_src[csr_src[off + i]];
    s0 += __expf(lrelu(as.x + ad.x) - m0);
    s1 += __expf(lrelu(as.y + ad.y) - m1);
    s2 += __expf(lrelu(as.z + ad.z) - m2);
    s3 += __expf(lrelu(as.w + ad.w) - m3);
  }
  #pragma unroll
  for (int st = 32; st > 0; st >>= 1){
    s0 += __shfl_xor(s0, st); s1 += __shfl_xor(s1, st);
    s2 += __shfl_xor(s2, st); s3 += __shfl_xor(s3, st);
  }
  float i0 = 1.f / (s0 + EPS_C), i1 = 1.f / (s1 + EPS_C);
  float i2 = 1.f / (s2 + EPS_C), i3 = 1.f / (s3 + EPS_C);
  if (have0){
    int eid = csr_eid[off + lane];
    *reinterpret_cast<float4*>(&alpha1_out[(size_t)eid * 4]) =
        make_float4(__expf(e0.x - m0) * i0, __expf(e0.y - m1) * i1,
                    __expf(e0.z - m2) * i2, __expf(e0.w - m3) * i3);
  }
  for (int i = lane + 64; i < deg; i += 64){
    int slot = off + i;
    float4 as = a_src[csr_src[slot]];
    int eid = csr_eid[slot];
    *reinterpret_cast<float4*>(&alpha1_out[(size_t)eid * 4]) =
        make_float4(__expf(lrelu(as.x + ad.x) - m0) * i0,
                    __expf(lrelu(as.y + ad.y) - m1) * i1,
                    __expf(lrelu(as.z + ad.z) - m2) * i2,
                    __expf(lrelu(as.w + ad.w) - m3) * i3);
  }
  int head = lane >> 4;
  float mh  = head == 0 ? m0 : head == 1 ? m1 : head == 2 ? m2 : m3;
  float ih  = head == 0 ? i0 : head == 1 ? i1 : head == 2 ? i2 : i3;
  float adh = head == 0 ? ad.x : head == 1 ? ad.y : head == 2 ? ad.z : ad.w;
  float4 accA = make_float4(0.f, 0.f, 0.f, 0.f);
  float4 accB = make_float4(0.f, 0.f, 0.f, 0.f);
  float4 accC = make_float4(0.f, 0.f, 0.f, 0.f);
  float4 accD = make_float4(0.f, 0.f, 0.f, 0.f);
  int j = 0;
  for (; j + 3 < deg; j += 4){
    int sA = csr_src[off + j];
    int sB = csr_src[off + j + 1];
    int sC = csr_src[off + j + 2];
    int sD = csr_src[off + j + 3];
    float alA = __expf(lrelu(a_src_f[(size_t)sA * 4 + head] + adh) - mh) * ih;
    float alB = __expf(lrelu(a_src_f[(size_t)sB * 4 + head] + adh) - mh) * ih;
    float alC = __expf(lrelu(a_src_f[(size_t)sC * 4 + head] + adh) - mh) * ih;
    float alD = __expf(lrelu(a_src_f[(size_t)sD * 4 + head] + adh) - mh) * ih;
    float2 rA = *reinterpret_cast<const float2*>(&h1[(size_t)sA * 256 + lane * 4]);
    float2 rB = *reinterpret_cast<const float2*>(&h1[(size_t)sB * 256 + lane * 4]);
    float2 rC = *reinterpret_cast<const float2*>(&h1[(size_t)sC * 256 + lane * 4]);
    float2 rD = *reinterpret_cast<const float2*>(&h1[(size_t)sD * 256 + lane * 4]);
    float2 fA0 = __half22float2(*reinterpret_cast<__half2*>(&rA.x));
    float2 fA1 = __half22float2(*reinterpret_cast<__half2*>(&rA.y));
    float2 fB0 = __half22float2(*reinterpret_cast<__half2*>(&rB.x));
    float2 fB1 = __half22float2(*reinterpret_cast<__half2*>(&rB.y));
    float2 fC0 = __half22float2(*reinterpret_cast<__half2*>(&rC.x));
    float2 fC1 = __half22float2(*reinterpret_cast<__half2*>(&rC.y));
    float2 fD0 = __half22float2(*reinterpret_cast<__half2*>(&rD.x));
    float2 fD1 = __half22float2(*reinterpret_cast<__half2*>(&rD.y));
    accA.x += alA * fA0.x; accA.y += alA * fA0.y; accA.z += alA * fA1.x; accA.w += alA * fA1.y;
    accB.x += alB * fB0.x; accB.y += alB * fB0.y; accB.z += alB * fB1.x; accB.w += alB * fB1.y;
    accC.x += alC * fC0.x; accC.y += alC * fC0.y; accC.z += alC * fC1.x; accC.w += alC * fC1.y;
    accD.x += alD * fD0.x; accD.y += alD * fD0.y; accD.z += alD * fD1.x; accD.w += alD * fD1.y;
  }
  for (; j < deg; ++j){
    int sA = csr_src[off + j];
    float alA = __expf(lrelu(a_src_f[(size_t)sA * 4 + head] + adh) - mh) * ih;
    float2 rA = *reinterpret_cast<const float2*>(&h1[(size_t)sA * 256 + lane * 4]);
    float2 fA0 = __half22float2(*reinterpret_cast<__half2*>(&rA.x));
    float2 fA1 = __half22float2(*reinterpret_cast<__half2*>(&rA.y));
    accA.x += alA * fA0.x; accA.y += alA * fA0.y; accA.z += alA * fA1.x; accA.w += alA * fA1.y;
  }
  accA.x += accB.x + accC.x + accD.x;
  accA.y += accB.y + accC.y + accD.y;
  accA.z += accB.z + accC.z + accD.z;
  accA.w += accB.w + accC.w + accD.w;
  float4 b = *reinterpret_cast<const float4*>(&bias[lane * 4]);
  float4 o = make_float4(eluf(accA.x + b.x), eluf(accA.y + b.y),
                         eluf(accA.z + b.z), eluf(accA.w + b.w));
  *reinterpret_cast<float4*>(&h1b[(size_t)n * 256 + lane * 4]) = o;
}

// ---------------- layer 2 GEMM: h2pre = h1b @ W2 [N,256]x[256,32] ----------------
__global__ __launch_bounds__(256) void gemm2_kernel(const float* __restrict__ h1b,
    const float* __restrict__ W2, const float* __restrict__ att_src2,
    const float* __restrict__ att_dst2, float* __restrict__ h2pre,
    float* __restrict__ a_src2, float* __restrict__ a_dst2, int N){
  __shared__ float As[128][33];
  __shared__ float Bs[32][33];
  int tid = threadIdx.x;
  int tx = tid & 15, ty = tid >> 4;
  int rowBase = blockIdx.x * 128;
  float acc[8][2] = {};
  float4 pa[4], pb;

  #pragma unroll
  for (int it = 0; it < 4; ++it){
    int li = it * 256 + tid;
    int r = li >> 3, kk = (li & 7) << 2;
    int row = rowBase + r;
    pa[it] = (row < N) ? *reinterpret_cast<const float4*>(&h1b[(size_t)row * 256 + kk])
                       : make_float4(0.f, 0.f, 0.f, 0.f);
  }
  {
    int kr = tid >> 3, c4 = (tid & 7) << 2;
    pb = *reinterpret_cast<const float4*>(&W2[(size_t)kr * 32 + c4]);
  }
  #pragma unroll
  for (int it = 0; it < 4; ++it){
    int li = it * 256 + tid;
    int r = li >> 3, kk = (li & 7) << 2;
    As[r][kk] = pa[it].x; As[r][kk + 1] = pa[it].y;
    As[r][kk + 2] = pa[it].z; As[r][kk + 3] = pa[it].w;
  }
  {
    int kr = tid >> 3, c4 = (tid & 7) << 2;
    Bs[kr][c4] = pb.x; Bs[kr][c4 + 1] = pb.y; Bs[kr][c4 + 2] = pb.z; Bs[kr][c4 + 3] = pb.w;
  }
  __syncthreads();

  for (int k0 = 0; k0 < 256; k0 += 32){
    bool more = (k0 + 32) < 256;
    if (more){
      #pragma unroll
      for (int it = 0; it < 4; ++it){
        int li = it * 256 + tid;
        int r = li >> 3, kk = (li & 7) << 2;
        int row = rowBase + r;
        pa[it] = (row < N) ? *reinterpret_cast<const float4*>(&h1b[(size_t)row * 256 + k0 + 32 + kk])
                           : make_float4(0.f, 0.f, 0.f, 0.f);
      }
      int kr = tid >> 3, c4 = (tid & 7) << 2;
      pb = *reinterpret_cast<const float4*>(&W2[(size_t)(k0 + 32 + kr) * 32 + c4]);
    }
    #pragma unroll
    for (int kk = 0; kk < 32; ++kk){
      float b0 = Bs[kk][tx * 2], b1 = Bs[kk][tx * 2 + 1];
      #pragma unroll
      for (int j = 0; j < 8; ++j){
        float a = As[ty + 16 * j][kk];
        acc[j][0] += a * b0; acc[j][1] += a * b1;
      }
    }
    if (more){
      __syncthreads();
      #pragma unroll
      for (int it = 0; it < 4; ++it){
        int li = it * 256 + tid;
        int r = li >> 3, kk = (li & 7) << 2;
        As[r][kk] = pa[it].x; As[r][kk + 1] = pa[it].y;
        As[r][kk + 2] = pa[it].z; As[r][kk + 3] = pa[it].w;
      }
      int kr = tid >> 3, c4 = (tid & 7) << 2;
      Bs[kr][c4] = pb.x; Bs[kr][c4 + 1] = pb.y; Bs[kr][c4 + 2] = pb.z; Bs[kr][c4 + 3] = pb.w;
      __syncthreads();
    }
  }
  #pragma unroll
  for (int j = 0; j < 8; ++j){
    int row = rowBase + ty + 16 * j;
    if (row < N)
      *reinterpret_cast<float2*>(&h2pre[(size_t)row * 32 + tx * 2]) =
          make_float2(acc[j][0], acc[j][1]);
  }
  float s0 = att_src2[tx * 2], s1 = att_src2[tx * 2 + 1];
  float d0 = att_dst2[tx * 2], d1 = att_dst2[tx * 2 + 1];
  float ps[8], pd[8];
  #pragma unroll
  for (int j = 0; j < 8; ++j){
    ps[j] = acc[j][0] * s0 + acc[j][1] * s1;
    pd[j] = acc[j][0] * d0 + acc[j][1] * d1;
  }
  #pragma unroll
  for (int st = 8; st > 0; st >>= 1){
    #pragma unroll
    for (int j = 0; j < 8; ++j){
      ps[j] += __shfl_xor(ps[j], st);
      pd[j] += __shfl_xor(pd[j], st);
    }
  }
  if (tx == 0){
    #pragma unroll
    for (int j = 0; j < 8; ++j){
      int row = rowBase + ty + 16 * j;
      if (row < N){
        a_src2[row] = ps[j];
        a_dst2[row] = pd[j];
      }
    }
  }
}

// ---------------- layer 2 node kernel: softmax + aggregate + bias ----------------
__global__ __launch_bounds__(256) void node2_kernel(
    const float* __restrict__ h2pre, const float* __restrict__ a_src2,
    const float* __restrict__ a_dst2, const int* __restrict__ offsets,
    const int* __restrict__ csr_src, const int* __restrict__ csr_eid,
    const float* __restrict__ bias2, float* __restrict__ out_h2,
    float* __restrict__ alpha2_out, int N){
  int gid = blockIdx.x * blockDim.x + threadIdx.x;
  int n = gid >> 6, lane = gid & 63;
  if (n >= N) return;
  int off = offsets[n], deg = offsets[n + 1] - off;
  float adn = a_dst2[n];
  bool have0 = (lane < deg);
  float e0 = -INFINITY;
  if (have0) e0 = lrelu(a_src2[csr_src[off + lane]] + adn);
  float m = e0;
  for (int i = lane + 64; i < deg; i += 64)
    m = fmaxf(m, lrelu(a_src2[csr_src[off + i]] + adn));
  #pragma unroll
  for (int st = 32; st > 0; st >>= 1) m = fmaxf(m, __shfl_xor(m, st));
  float s = have0 ? __expf(e0 - m) : 0.f;
  for (int i = lane + 64; i < deg; i += 64)
    s += __expf(lrelu(a_src2[csr_src[off + i]] + adn) - m);
  #pragma unroll
  for (int st = 32; st > 0; st >>= 1) s += __shfl_xor(s, st);
  float inv = 1.f / (s + EPS_C);
  if (have0) alpha2_out[csr_eid[off + lane]] = __expf(e0 - m) * inv;
  for (int i = lane + 64; i < deg; i += 64){
    int slot = off + i;
    alpha2_out[csr_eid[slot]] = __expf(lrelu(a_src2[csr_src[slot]] + adn) - m) * inv;
  }
  int c = lane & 31, half = lane >> 5;
  float acc = 0.f;
  for (int j = half; j < deg; j += 2){
    int src = csr_src[off + j];
    float al = __expf(lrelu(a_src2[src] + adn) - m) * inv;
    acc += al * h2pre[(size_t)src * 32 + c];
  }
  acc += __shfl_xor(acc, 32);
  if (lane < 32) out_h2[(size_t)n * 32 + c] = acc + bias2[c];
}

// ---------------- echo edge_index (as float) into output regions 1 and 3 ----------------
__global__ void edge_out_kernel(const int* __restrict__ ei, float* __restrict__ out1,
                                float* __restrict__ out3, int n2e){
  int i = blockIdx.x * blockDim.x + threadIdx.x;
  if (i < n2e){
    float v = (float)ei[i];
    out1[i] = v; out3[i] = v;
  }
}

extern "C" void kernel_launch(void* const* d_in, const int* in_sizes, int n_in,
                              void* d_out, int out_size, void* d_ws, size_t ws_size,
                              hipStream_t stream){
  const float* x        = (const float*)d_in[0];
  const int*   ei       = (const int*)d_in[1];
  const float* W1       = (const float*)d_in[2];
  const float* att_src1 = (const float*)d_in[3];
  const float* att_dst1 = (const float*)d_in[4];
  const float* bias1    = (const float*)d_in[5];
  const float* W2       = (const float*)d_in[6];
  const float* att_src2 = (const float*)d_in[7];
  const float* att_dst2 = (const float*)d_in[8];
  const float* bias2    = (const float*)d_in[9];
  float* out = (float*)d_out;
  (void)n_in; (void)out_size; (void)ws_size;

  const int N = in_sizes[0] / 128;
  const int E = in_sizes[1] / 2;
  const int* src = ei;
  const int* dst = ei + E;

  char* ws = (char*)d_ws;
  size_t o = 0;
  auto alloc = [&](size_t bytes) -> void* {
    void* p = ws + o;
    o += (bytes + 255) & ~(size_t)255;
    return p;
  };
  __half* h1      = (__half*)alloc((size_t)N * 256 * 2);   // fp16 gather payload
  __half* x16     = (__half*)alloc((size_t)N * 128 * 2);   // fp16 input
  __half* W1t     = (__half*)alloc((size_t)256 * 128 * 2); // fp16 W1 transposed [col][k]
  float*  h1b     = (float*)alloc((size_t)N * 256 * 4);
  float*  h2pre   = (float*)alloc((size_t)N * 32 * 4);
  float*  a_src1  = (float*)alloc((size_t)N * 16);
  float*  a_dst1  = (float*)alloc((size_t)N * 16);
  float*  a_src2  = (float*)alloc((size_t)N * 4);
  float*  a_dst2  = (float*)alloc((size_t)N * 4);
  int*    deg     = (int*)alloc((size_t)N * 4);
  int*    offsets = (int*)alloc((size_t)(N + 1) * 4);
  int*    cursor  = (int*)alloc((size_t)N * 4);
  int*    csr_src = (int*)alloc((size_t)E * 4);
  int*    csr_eid = (int*)alloc((size_t)E * 4);

  const size_t OFF1 = (size_t)N * 32;       // edge_index copy 1
  const size_t OFF2 = OFF1 + (size_t)2 * E; // alpha1 [E,4]
  const size_t OFF3 = OFF2 + (size_t)E * 4; // edge_index copy 2
  const size_t OFF4 = OFF3 + (size_t)2 * E; // alpha2 [E]

  // input converts
  int n4 = (N * 128) / 4;
  hipLaunchKernelGGL(cvt_x_kernel, dim3((n4 + 255) / 256), dim3(256), 0, stream, x, x16, n4);
  hipLaunchKernelGGL(cvt_w1_kernel, dim3(128), dim3(256), 0, stream, W1, W1t);
  // CSR build
  hipLaunchKernelGGL(zero_int_kernel, dim3((N + 255) / 256), dim3(256), 0, stream, deg, N);
  hipLaunchKernelGGL(count_deg_kernel, dim3((E + 255) / 256), dim3(256), 0, stream, dst, deg, E);
  hipLaunchKernelGGL(scan_kernel, dim3(1), dim3(1024), 0, stream, deg, offsets, cursor, N);
  hipLaunchKernelGGL(scatter_kernel, dim3((E + 255) / 256), dim3(256), 0, stream,
                     src, dst, cursor, csr_src, csr_eid, E);
  // layer 1 (MFMA GEMM, attention dots fused)
  hipLaunchKernelGGL(gemm1_kernel, dim3((N + 127) / 128, 4), dim3(256), 0, stream,
                     x16, W1t, att_src1, att_dst1, h1, a_src1, a_dst1, N);
  hipLaunchKernelGGL(node1_kernel, dim3((N * 64 + 255) / 256), dim3(256), 0, stream,
                     h1, (const float4*)a_src1, (const float*)a_src1, (const float4*)a_dst1,
                     offsets, csr_src, csr_eid, bias1, h1b, out + OFF2, N);
  // layer 2
  hipLaunchKernelGGL(gemm2_kernel, dim3((N + 127) / 128), dim3(256), 0, stream,
                     h1b, W2, att_src2, att_dst2, h2pre, a_src2, a_dst2, N);
  hipLaunchKernelGGL(node2_kernel, dim3((N * 64 + 255) / 256), dim3(256), 0, stream,
                     h2pre, a_src2, a_dst2, offsets, csr_src, csr_eid, bias2,
                     out, out + OFF4, N);
  // edge_index echo
  hipLaunchKernelGGL(edge_out_kernel, dim3((2 * E + 255) / 256), dim3(256), 0, stream,
                     ei, out + OFF1, out + OFF3, 2 * E);
}

// Round 8
// 389.874 us; speedup vs baseline: 1.7591x; 1.2509x over previous
//
#include <hip/hip_runtime.h>
#include <hip/hip_fp16.h>
#include <math.h>

#define NEG_SLOPE 0.2f
#define EPS_C 1e-16f

typedef _Float16 f16x8 __attribute__((ext_vector_type(8)));
typedef float f32x4 __attribute__((ext_vector_type(4)));

__device__ __forceinline__ float lrelu(float x){ return x > 0.f ? x : NEG_SLOPE * x; }
__device__ __forceinline__ float eluf(float x){ return x > 0.f ? x : expm1f(x); }

// ---------------- CSR build (by dst) ----------------
__global__ void zero_int_kernel(int* __restrict__ p, int n){
  int i = blockIdx.x * blockDim.x + threadIdx.x;
  if (i < n) p[i] = 0;
}

__global__ void count_deg_kernel(const int* __restrict__ dst, int* __restrict__ deg, int E){
  int i = blockIdx.x * blockDim.x + threadIdx.x;
  if (i < E) atomicAdd(&deg[dst[i]], 1);
}

// R7: old single-block scan was 110us at 0.14% occupancy (serial latency chain).
// 3-phase parallel scan: per-block scan -> block-sum scan -> add base. ~15us.
__global__ __launch_bounds__(256) void scan1_kernel(const int* __restrict__ deg,
    int* __restrict__ offsets, int* __restrict__ blockSums, int N){
  __shared__ int sm[256];
  int b = blockIdx.x, t = threadIdx.x;
  int i = b * 256 + t;
  int v = (i < N) ? deg[i] : 0;
  sm[t] = v;
  __syncthreads();
  #pragma unroll
  for (int st = 1; st < 256; st <<= 1){
    int add = (t >= st) ? sm[t - st] : 0;
    __syncthreads();
    sm[t] += add;
    __syncthreads();
  }
  if (i < N) offsets[i] = sm[t] - v;       // exclusive local prefix
  if (t == 255) blockSums[b] = sm[255];    // block total
}

__global__ __launch_bounds__(256) void scan2_kernel(const int* __restrict__ blockSums,
    int* __restrict__ blockBase, int* __restrict__ offsetsN, int nb){
  __shared__ int sm[256];
  int t = threadIdx.x;
  int v = (t < nb) ? blockSums[t] : 0;
  sm[t] = v;
  __syncthreads();
  #pragma unroll
  for (int st = 1; st < 256; st <<= 1){
    int add = (t >= st) ? sm[t - st] : 0;
    __syncthreads();
    sm[t] += add;
    __syncthreads();
  }
  if (t < nb) blockBase[t] = sm[t] - v;    // exclusive
  if (t == 255) *offsetsN = sm[255];       // total == E
}

__global__ __launch_bounds__(256) void scan3_kernel(int* __restrict__ offsets,
    const int* __restrict__ blockBase, int* __restrict__ cursor, int N){
  int b = blockIdx.x, t = threadIdx.x;
  int i = b * 256 + t;
  if (i < N){
    int v = offsets[i] + blockBase[b];
    offsets[i] = v;
    cursor[i] = v;
  }
}

__global__ void scatter_kernel(const int* __restrict__ src, const int* __restrict__ dst,
                               int* __restrict__ cursor, int* __restrict__ csr_src,
                               int* __restrict__ csr_eid, int E){
  int i = blockIdx.x * blockDim.x + threadIdx.x;
  if (i < E){
    int d = dst[i];
    int p = atomicAdd(&cursor[d], 1);
    csr_src[p] = src[i];
    csr_eid[p] = i;
  }
}

// ---------------- input converts: x -> fp16, W1 -> fp16 transposed ----------------
__global__ void cvt_x_kernel(const float* __restrict__ x, __half* __restrict__ x16, int n4){
  int i = blockIdx.x * blockDim.x + threadIdx.x;
  if (i < n4){
    float4 v = *reinterpret_cast<const float4*>(&x[(size_t)i * 4]);
    __half2 h01 = __floats2half2_rn(v.x, v.y);
    __half2 h23 = __floats2half2_rn(v.z, v.w);
    uint2 pack;
    pack.x = *reinterpret_cast<unsigned int*>(&h01);
    pack.y = *reinterpret_cast<unsigned int*>(&h23);
    *reinterpret_cast<uint2*>(&x16[(size_t)i * 4]) = pack;
  }
}

// W1 [128][256] fp32 -> W1t [256][128] fp16
__global__ void cvt_w1_kernel(const float* __restrict__ W1, __half* __restrict__ W1t){
  int i = blockIdx.x * blockDim.x + threadIdx.x;   // 32768 threads
  int k = i >> 8, c = i & 255;
  if (i < 128 * 256) W1t[(size_t)c * 128 + k] = __float2half(W1[(size_t)k * 256 + c]);
}

// ---------------- layer 1 GEMM via MFMA: h1 = x16 @ W1t  [N,128]x[128,256] ----
__global__ __launch_bounds__(256) void gemm1_kernel(const __half* __restrict__ x16,
    const __half* __restrict__ W1t, const float* __restrict__ att_src,
    const float* __restrict__ att_dst, __half* __restrict__ h1,
    float* __restrict__ a_src_f, float* __restrict__ a_dst_f, int N){
  __shared__ _Float16 As[128 * 136];   // x tile [row][k]
  __shared__ _Float16 Bs[64 * 136];    // W1t tile [col][k]
  int tid = threadIdx.x;
  int lane = tid & 63, wid = tid >> 6;
  int rowBase = blockIdx.x * 128;
  int head = blockIdx.y;
  int colBase = head * 64;

  #pragma unroll
  for (int it = 0; it < 8; ++it){
    int li = it * 256 + tid;
    int r = li >> 4, seg = li & 15;
    int grow = rowBase + r;
    f16x8 v = {};
    if (grow < N) v = *reinterpret_cast<const f16x8*>(&x16[(size_t)grow * 128 + seg * 8]);
    *reinterpret_cast<f16x8*>(&As[r * 136 + seg * 8]) = v;
  }
  #pragma unroll
  for (int it = 0; it < 4; ++it){
    int li = it * 256 + tid;
    int c = li >> 4, seg = li & 15;
    f16x8 v = *reinterpret_cast<const f16x8*>(&W1t[(size_t)(colBase + c) * 128 + seg * 8]);
    *reinterpret_cast<f16x8*>(&Bs[c * 136 + seg * 8]) = v;
  }
  __syncthreads();

  f32x4 acc[2][4] = {};
  int l15 = lane & 15, l4 = lane >> 4;
  #pragma unroll
  for (int ks = 0; ks < 4; ++ks){
    int kOff = ks * 32 + l4 * 8;
    f16x8 a0 = *reinterpret_cast<const f16x8*>(&As[(wid * 32 + l15) * 136 + kOff]);
    f16x8 a1 = *reinterpret_cast<const f16x8*>(&As[(wid * 32 + 16 + l15) * 136 + kOff]);
    #pragma unroll
    for (int cc = 0; cc < 4; ++cc){
      f16x8 b = *reinterpret_cast<const f16x8*>(&Bs[(cc * 16 + l15) * 136 + kOff]);
      acc[0][cc] = __builtin_amdgcn_mfma_f32_16x16x32_f16(a0, b, acc[0][cc], 0, 0, 0);
      acc[1][cc] = __builtin_amdgcn_mfma_f32_16x16x32_f16(a1, b, acc[1][cc], 0, 0, 0);
    }
  }

  #pragma unroll
  for (int rr = 0; rr < 2; ++rr){
    #pragma unroll
    for (int i = 0; i < 4; ++i){
      int row = rowBase + wid * 32 + rr * 16 + l4 * 4 + i;
      if (row < N){
        #pragma unroll
        for (int cc = 0; cc < 4; ++cc)
          h1[(size_t)row * 256 + colBase + cc * 16 + l15] = __float2half(acc[rr][cc][i]);
      }
    }
  }
  float sw[4], dw[4];
  #pragma unroll
  for (int cc = 0; cc < 4; ++cc){
    sw[cc] = att_src[colBase + cc * 16 + l15];
    dw[cc] = att_dst[colBase + cc * 16 + l15];
  }
  #pragma unroll
  for (int rr = 0; rr < 2; ++rr){
    #pragma unroll
    for (int i = 0; i < 4; ++i){
      float ts = 0.f, td = 0.f;
      #pragma unroll
      for (int cc = 0; cc < 4; ++cc){
        ts += acc[rr][cc][i] * sw[cc];
        td += acc[rr][cc][i] * dw[cc];
      }
      #pragma unroll
      for (int st = 8; st > 0; st >>= 1){
        ts += __shfl_xor(ts, st);
        td += __shfl_xor(td, st);
      }
      int row = rowBase + wid * 32 + rr * 16 + l4 * 4 + i;
      if (l15 == 0 && row < N){
        a_src_f[(size_t)row * 4 + head] = ts;
        a_dst_f[(size_t)row * 4 + head] = td;
      }
    }
  }
}

// ---------------- layer 1 node kernel: softmax + aggregate + bias + ELU ----------------
__global__ __launch_bounds__(256) void node1_kernel(
    const __half* __restrict__ h1, const float4* __restrict__ a_src,
    const float* __restrict__ a_src_f, const float4* __restrict__ a_dst,
    const int* __restrict__ offsets, const int* __restrict__ csr_src,
    const int* __restrict__ csr_eid, const float* __restrict__ bias,
    float* __restrict__ h1b, float* __restrict__ alpha1_out, int N){
  int gid = blockIdx.x * blockDim.x + threadIdx.x;
  int n = gid >> 6, lane = gid & 63;
  if (n >= N) return;
  int off = offsets[n];
  int deg = offsets[n + 1] - off;
  float4 ad = a_dst[n];
  bool have0 = (lane < deg);
  float4 e0 = make_float4(-INFINITY, -INFINITY, -INFINITY, -INFINITY);
  if (have0){
    float4 as = a_src[csr_src[off + lane]];
    e0 = make_float4(lrelu(as.x + ad.x), lrelu(as.y + ad.y),
                     lrelu(as.z + ad.z), lrelu(as.w + ad.w));
  }
  float m0 = e0.x, m1 = e0.y, m2 = e0.z, m3 = e0.w;
  for (int i = lane + 64; i < deg; i += 64){
    float4 as = a_src[csr_src[off + i]];
    m0 = fmaxf(m0, lrelu(as.x + ad.x));
    m1 = fmaxf(m1, lrelu(as.y + ad.y));
    m2 = fmaxf(m2, lrelu(as.z + ad.z));
    m3 = fmaxf(m3, lrelu(as.w + ad.w));
  }
  #pragma unroll
  for (int st = 32; st > 0; st >>= 1){
    m0 = fmaxf(m0, __shfl_xor(m0, st));
    m1 = fmaxf(m1, __shfl_xor(m1, st));
    m2 = fmaxf(m2, __shfl_xor(m2, st));
    m3 = fmaxf(m3, __shfl_xor(m3, st));
  }
  float s0 = 0.f, s1 = 0.f, s2 = 0.f, s3 = 0.f;
  if (have0){
    s0 = __expf(e0.x - m0); s1 = __expf(e0.y - m1);
    s2 = __expf(e0.z - m2); s3 = __expf(e0.w - m3);
  }
  for (int i = lane + 64; i < deg; i += 64){
    float4 as = a_src[csr_src[off + i]];
    s0 += __expf(lrelu(as.x + ad.x) - m0);
    s1 += __expf(lrelu(as.y + ad.y) - m1);
    s2 += __expf(lrelu(as.z + ad.z) - m2);
    s3 += __expf(lrelu(as.w + ad.w) - m3);
  }
  #pragma unroll
  for (int st = 32; st > 0; st >>= 1){
    s0 += __shfl_xor(s0, st); s1 += __shfl_xor(s1, st);
    s2 += __shfl_xor(s2, st); s3 += __shfl_xor(s3, st);
  }
  float i0 = 1.f / (s0 + EPS_C), i1 = 1.f / (s1 + EPS_C);
  float i2 = 1.f / (s2 + EPS_C), i3 = 1.f / (s3 + EPS_C);
  if (have0){
    int eid = csr_eid[off + lane];
    *reinterpret_cast<float4*>(&alpha1_out[(size_t)eid * 4]) =
        make_float4(__expf(e0.x - m0) * i0, __expf(e0.y - m1) * i1,
                    __expf(e0.z - m2) * i2, __expf(e0.w - m3) * i3);
  }
  for (int i = lane + 64; i < deg; i += 64){
    int slot = off + i;
    float4 as = a_src[csr_src[slot]];
    int eid = csr_eid[slot];
    *reinterpret_cast<float4*>(&alpha1_out[(size_t)eid * 4]) =
        make_float4(__expf(lrelu(as.x + ad.x) - m0) * i0,
                    __expf(lrelu(as.y + ad.y) - m1) * i1,
                    __expf(lrelu(as.z + ad.z) - m2) * i2,
                    __expf(lrelu(as.w + ad.w) - m3) * i3);
  }
  int head = lane >> 4;
  float mh  = head == 0 ? m0 : head == 1 ? m1 : head == 2 ? m2 : m3;
  float ih  = head == 0 ? i0 : head == 1 ? i1 : head == 2 ? i2 : i3;
  float adh = head == 0 ? ad.x : head == 1 ? ad.y : head == 2 ? ad.z : ad.w;
  float4 accA = make_float4(0.f, 0.f, 0.f, 0.f);
  float4 accB = make_float4(0.f, 0.f, 0.f, 0.f);
  float4 accC = make_float4(0.f, 0.f, 0.f, 0.f);
  float4 accD = make_float4(0.f, 0.f, 0.f, 0.f);
  int j = 0;
  for (; j + 3 < deg; j += 4){
    int sA = csr_src[off + j];
    int sB = csr_src[off + j + 1];
    int sC = csr_src[off + j + 2];
    int sD = csr_src[off + j + 3];
    float alA = __expf(lrelu(a_src_f[(size_t)sA * 4 + head] + adh) - mh) * ih;
    float alB = __expf(lrelu(a_src_f[(size_t)sB * 4 + head] + adh) - mh) * ih;
    float alC = __expf(lrelu(a_src_f[(size_t)sC * 4 + head] + adh) - mh) * ih;
    float alD = __expf(lrelu(a_src_f[(size_t)sD * 4 + head] + adh) - mh) * ih;
    float2 rA = *reinterpret_cast<const float2*>(&h1[(size_t)sA * 256 + lane * 4]);
    float2 rB = *reinterpret_cast<const float2*>(&h1[(size_t)sB * 256 + lane * 4]);
    float2 rC = *reinterpret_cast<const float2*>(&h1[(size_t)sC * 256 + lane * 4]);
    float2 rD = *reinterpret_cast<const float2*>(&h1[(size_t)sD * 256 + lane * 4]);
    float2 fA0 = __half22float2(*reinterpret_cast<__half2*>(&rA.x));
    float2 fA1 = __half22float2(*reinterpret_cast<__half2*>(&rA.y));
    float2 fB0 = __half22float2(*reinterpret_cast<__half2*>(&rB.x));
    float2 fB1 = __half22float2(*reinterpret_cast<__half2*>(&rB.y));
    float2 fC0 = __half22float2(*reinterpret_cast<__half2*>(&rC.x));
    float2 fC1 = __half22float2(*reinterpret_cast<__half2*>(&rC.y));
    float2 fD0 = __half22float2(*reinterpret_cast<__half2*>(&rD.x));
    float2 fD1 = __half22float2(*reinterpret_cast<__half2*>(&rD.y));
    accA.x += alA * fA0.x; accA.y += alA * fA0.y; accA.z += alA * fA1.x; accA.w += alA * fA1.y;
    accB.x += alB * fB0.x; accB.y += alB * fB0.y; accB.z += alB * fB1.x; accB.w += alB * fB1.y;
    accC.x += alC * fC0.x; accC.y += alC * fC0.y; accC.z += alC * fC1.x; accC.w += alC * fC1.y;
    accD.x += alD * fD0.x; accD.y += alD * fD0.y; accD.z += alD * fD1.x; accD.w += alD * fD1.y;
  }
  for (; j < deg; ++j){
    int sA = csr_src[off + j];
    float alA = __expf(lrelu(a_src_f[(size_t)sA * 4 + head] + adh) - mh) * ih;
    float2 rA = *reinterpret_cast<const float2*>(&h1[(size_t)sA * 256 + lane * 4]);
    float2 fA0 = __half22float2(*reinterpret_cast<__half2*>(&rA.x));
    float2 fA1 = __half22float2(*reinterpret_cast<__half2*>(&rA.y));
    accA.x += alA * fA0.x; accA.y += alA * fA0.y; accA.z += alA * fA1.x; accA.w += alA * fA1.y;
  }
  accA.x += accB.x + accC.x + accD.x;
  accA.y += accB.y + accC.y + accD.y;
  accA.z += accB.z + accC.z + accD.z;
  accA.w += accB.w + accC.w + accD.w;
  float4 b = *reinterpret_cast<const float4*>(&bias[lane * 4]);
  float4 o = make_float4(eluf(accA.x + b.x), eluf(accA.y + b.y),
                         eluf(accA.z + b.z), eluf(accA.w + b.w));
  *reinterpret_cast<float4*>(&h1b[(size_t)n * 256 + lane * 4]) = o;
}

// ---------------- layer 2 GEMM: h2pre = h1b @ W2 [N,256]x[256,32] ----------------
__global__ __launch_bounds__(256) void gemm2_kernel(const float* __restrict__ h1b,
    const float* __restrict__ W2, const float* __restrict__ att_src2,
    const float* __restrict__ att_dst2, float* __restrict__ h2pre,
    float* __restrict__ a_src2, float* __restrict__ a_dst2, int N){
  __shared__ float As[128][33];
  __shared__ float Bs[32][33];
  int tid = threadIdx.x;
  int tx = tid & 15, ty = tid >> 4;
  int rowBase = blockIdx.x * 128;
  float acc[8][2] = {};
  float4 pa[4], pb;

  #pragma unroll
  for (int it = 0; it < 4; ++it){
    int li = it * 256 + tid;
    int r = li >> 3, kk = (li & 7) << 2;
    int row = rowBase + r;
    pa[it] = (row < N) ? *reinterpret_cast<const float4*>(&h1b[(size_t)row * 256 + kk])
                       : make_float4(0.f, 0.f, 0.f, 0.f);
  }
  {
    int kr = tid >> 3, c4 = (tid & 7) << 2;
    pb = *reinterpret_cast<const float4*>(&W2[(size_t)kr * 32 + c4]);
  }
  #pragma unroll
  for (int it = 0; it < 4; ++it){
    int li = it * 256 + tid;
    int r = li >> 3, kk = (li & 7) << 2;
    As[r][kk] = pa[it].x; As[r][kk + 1] = pa[it].y;
    As[r][kk + 2] = pa[it].z; As[r][kk + 3] = pa[it].w;
  }
  {
    int kr = tid >> 3, c4 = (tid & 7) << 2;
    Bs[kr][c4] = pb.x; Bs[kr][c4 + 1] = pb.y; Bs[kr][c4 + 2] = pb.z; Bs[kr][c4 + 3] = pb.w;
  }
  __syncthreads();

  for (int k0 = 0; k0 < 256; k0 += 32){
    bool more = (k0 + 32) < 256;
    if (more){
      #pragma unroll
      for (int it = 0; it < 4; ++it){
        int li = it * 256 + tid;
        int r = li >> 3, kk = (li & 7) << 2;
        int row = rowBase + r;
        pa[it] = (row < N) ? *reinterpret_cast<const float4*>(&h1b[(size_t)row * 256 + k0 + 32 + kk])
                           : make_float4(0.f, 0.f, 0.f, 0.f);
      }
      int kr = tid >> 3, c4 = (tid & 7) << 2;
      pb = *reinterpret_cast<const float4*>(&W2[(size_t)(k0 + 32 + kr) * 32 + c4]);
    }
    #pragma unroll
    for (int kk = 0; kk < 32; ++kk){
      float b0 = Bs[kk][tx * 2], b1 = Bs[kk][tx * 2 + 1];
      #pragma unroll
      for (int j = 0; j < 8; ++j){
        float a = As[ty + 16 * j][kk];
        acc[j][0] += a * b0; acc[j][1] += a * b1;
      }
    }
    if (more){
      __syncthreads();
      #pragma unroll
      for (int it = 0; it < 4; ++it){
        int li = it * 256 + tid;
        int r = li >> 3, kk = (li & 7) << 2;
        As[r][kk] = pa[it].x; As[r][kk + 1] = pa[it].y;
        As[r][kk + 2] = pa[it].z; As[r][kk + 3] = pa[it].w;
      }
      int kr = tid >> 3, c4 = (tid & 7) << 2;
      Bs[kr][c4] = pb.x; Bs[kr][c4 + 1] = pb.y; Bs[kr][c4 + 2] = pb.z; Bs[kr][c4 + 3] = pb.w;
      __syncthreads();
    }
  }
  #pragma unroll
  for (int j = 0; j < 8; ++j){
    int row = rowBase + ty + 16 * j;
    if (row < N)
      *reinterpret_cast<float2*>(&h2pre[(size_t)row * 32 + tx * 2]) =
          make_float2(acc[j][0], acc[j][1]);
  }
  float s0 = att_src2[tx * 2], s1 = att_src2[tx * 2 + 1];
  float d0 = att_dst2[tx * 2], d1 = att_dst2[tx * 2 + 1];
  float ps[8], pd[8];
  #pragma unroll
  for (int j = 0; j < 8; ++j){
    ps[j] = acc[j][0] * s0 + acc[j][1] * s1;
    pd[j] = acc[j][0] * d0 + acc[j][1] * d1;
  }
  #pragma unroll
  for (int st = 8; st > 0; st >>= 1){
    #pragma unroll
    for (int j = 0; j < 8; ++j){
      ps[j] += __shfl_xor(ps[j], st);
      pd[j] += __shfl_xor(pd[j], st);
    }
  }
  if (tx == 0){
    #pragma unroll
    for (int j = 0; j < 8; ++j){
      int row = rowBase + ty + 16 * j;
      if (row < N){
        a_src2[row] = ps[j];
        a_dst2[row] = pd[j];
      }
    }
  }
}

// ---------------- layer 2 node kernel: softmax + aggregate + bias ----------------
__global__ __launch_bounds__(256) void node2_kernel(
    const float* __restrict__ h2pre, const float* __restrict__ a_src2,
    const float* __restrict__ a_dst2, const int* __restrict__ offsets,
    const int* __restrict__ csr_src, const int* __restrict__ csr_eid,
    const float* __restrict__ bias2, float* __restrict__ out_h2,
    float* __restrict__ alpha2_out, int N){
  int gid = blockIdx.x * blockDim.x + threadIdx.x;
  int n = gid >> 6, lane = gid & 63;
  if (n >= N) return;
  int off = offsets[n], deg = offsets[n + 1] - off;
  float adn = a_dst2[n];
  bool have0 = (lane < deg);
  float e0 = -INFINITY;
  if (have0) e0 = lrelu(a_src2[csr_src[off + lane]] + adn);
  float m = e0;
  for (int i = lane + 64; i < deg; i += 64)
    m = fmaxf(m, lrelu(a_src2[csr_src[off + i]] + adn));
  #pragma unroll
  for (int st = 32; st > 0; st >>= 1) m = fmaxf(m, __shfl_xor(m, st));
  float s = have0 ? __expf(e0 - m) : 0.f;
  for (int i = lane + 64; i < deg; i += 64)
    s += __expf(lrelu(a_src2[csr_src[off + i]] + adn) - m);
  #pragma unroll
  for (int st = 32; st > 0; st >>= 1) s += __shfl_xor(s, st);
  float inv = 1.f / (s + EPS_C);
  if (have0) alpha2_out[csr_eid[off + lane]] = __expf(e0 - m) * inv;
  for (int i = lane + 64; i < deg; i += 64){
    int slot = off + i;
    alpha2_out[csr_eid[slot]] = __expf(lrelu(a_src2[csr_src[slot]] + adn) - m) * inv;
  }
  int c = lane & 31, half = lane >> 5;
  float acc = 0.f;
  for (int j = half; j < deg; j += 2){
    int src = csr_src[off + j];
    float al = __expf(lrelu(a_src2[src] + adn) - m) * inv;
    acc += al * h2pre[(size_t)src * 32 + c];
  }
  acc += __shfl_xor(acc, 32);
  if (lane < 32) out_h2[(size_t)n * 32 + c] = acc + bias2[c];
}

// ---------------- echo edge_index (as float) into output regions 1 and 3 ----------------
__global__ void edge_out_kernel(const int* __restrict__ ei, float* __restrict__ out1,
                                float* __restrict__ out3, int n2e){
  int i = blockIdx.x * blockDim.x + threadIdx.x;
  if (i < n2e){
    float v = (float)ei[i];
    out1[i] = v; out3[i] = v;
  }
}

extern "C" void kernel_launch(void* const* d_in, const int* in_sizes, int n_in,
                              void* d_out, int out_size, void* d_ws, size_t ws_size,
                              hipStream_t stream){
  const float* x        = (const float*)d_in[0];
  const int*   ei       = (const int*)d_in[1];
  const float* W1       = (const float*)d_in[2];
  const float* att_src1 = (const float*)d_in[3];
  const float* att_dst1 = (const float*)d_in[4];
  const float* bias1    = (const float*)d_in[5];
  const float* W2       = (const float*)d_in[6];
  const float* att_src2 = (const float*)d_in[7];
  const float* att_dst2 = (const float*)d_in[8];
  const float* bias2    = (const float*)d_in[9];
  float* out = (float*)d_out;
  (void)n_in; (void)out_size; (void)ws_size;

  const int N = in_sizes[0] / 128;
  const int E = in_sizes[1] / 2;
  const int* src = ei;
  const int* dst = ei + E;
  const int nb = (N + 255) / 256;   // scan blocks (196 for N=50000; scan2 handles nb<=256)

  char* ws = (char*)d_ws;
  size_t o = 0;
  auto alloc = [&](size_t bytes) -> void* {
    void* p = ws + o;
    o += (bytes + 255) & ~(size_t)255;
    return p;
  };
  __half* h1      = (__half*)alloc((size_t)N * 256 * 2);   // fp16 gather payload
  __half* x16     = (__half*)alloc((size_t)N * 128 * 2);   // fp16 input
  __half* W1t     = (__half*)alloc((size_t)256 * 128 * 2); // fp16 W1 transposed [col][k]
  float*  h1b     = (float*)alloc((size_t)N * 256 * 4);
  float*  h2pre   = (float*)alloc((size_t)N * 32 * 4);
  float*  a_src1  = (float*)alloc((size_t)N * 16);
  float*  a_dst1  = (float*)alloc((size_t)N * 16);
  float*  a_src2  = (float*)alloc((size_t)N * 4);
  float*  a_dst2  = (float*)alloc((size_t)N * 4);
  int*    deg     = (int*)alloc((size_t)N * 4);
  int*    offsets = (int*)alloc((size_t)(N + 1) * 4);
  int*    cursor  = (int*)alloc((size_t)N * 4);
  int*    csr_src = (int*)alloc((size_t)E * 4);
  int*    csr_eid = (int*)alloc((size_t)E * 4);
  int*    blockSums = (int*)alloc(256 * 4);
  int*    blockBase = (int*)alloc(256 * 4);

  const size_t OFF1 = (size_t)N * 32;       // edge_index copy 1
  const size_t OFF2 = OFF1 + (size_t)2 * E; // alpha1 [E,4]
  const size_t OFF3 = OFF2 + (size_t)E * 4; // edge_index copy 2
  const size_t OFF4 = OFF3 + (size_t)2 * E; // alpha2 [E]

  // input converts
  int n4 = (N * 128) / 4;
  hipLaunchKernelGGL(cvt_x_kernel, dim3((n4 + 255) / 256), dim3(256), 0, stream, x, x16, n4);
  hipLaunchKernelGGL(cvt_w1_kernel, dim3(128), dim3(256), 0, stream, W1, W1t);
  // CSR build (3-phase parallel scan)
  hipLaunchKernelGGL(zero_int_kernel, dim3((N + 255) / 256), dim3(256), 0, stream, deg, N);
  hipLaunchKernelGGL(count_deg_kernel, dim3((E + 255) / 256), dim3(256), 0, stream, dst, deg, E);
  hipLaunchKernelGGL(scan1_kernel, dim3(nb), dim3(256), 0, stream, deg, offsets, blockSums, N);
  hipLaunchKernelGGL(scan2_kernel, dim3(1), dim3(256), 0, stream, blockSums, blockBase,
                     offsets + N, nb);
  hipLaunchKernelGGL(scan3_kernel, dim3(nb), dim3(256), 0, stream, offsets, blockBase, cursor, N);
  hipLaunchKernelGGL(scatter_kernel, dim3((E + 255) / 256), dim3(256), 0, stream,
                     src, dst, cursor, csr_src, csr_eid, E);
  // layer 1 (MFMA GEMM, attention dots fused)
  hipLaunchKernelGGL(gemm1_kernel, dim3((N + 127) / 128, 4), dim3(256), 0, stream,
                     x16, W1t, att_src1, att_dst1, h1, a_src1, a_dst1, N);
  hipLaunchKernelGGL(node1_kernel, dim3((N * 64 + 255) / 256), dim3(256), 0, stream,
                     h1, (const float4*)a_src1, (const float*)a_src1, (const float4*)a_dst1,
                     offsets, csr_src, csr_eid, bias1, h1b, out + OFF2, N);
  // layer 2
  hipLaunchKernelGGL(gemm2_kernel, dim3((N + 127) / 128), dim3(256), 0, stream,
                     h1b, W2, att_src2, att_dst2, h2pre, a_src2, a_dst2, N);
  hipLaunchKernelGGL(node2_kernel, dim3((N * 64 + 255) / 256), dim3(256), 0, stream,
                     h2pre, a_src2, a_dst2, offsets, csr_src, csr_eid, bias2,
                     out, out + OFF4, N);
  // edge_index echo
  hipLaunchKernelGGL(edge_out_kernel, dim3((2 * E + 255) / 256), dim3(256), 0, stream,
                     ei, out + OFF1, out + OFF3, 2 * E);
}

// Round 10
// 361.407 us; speedup vs baseline: 1.8976x; 1.0788x over previous
//
#include <hip/hip_runtime.h>
#include <hip/hip_fp16.h>
#include <math.h>

#define NEG_SLOPE 0.2f
#define EPS_C 1e-16f

typedef _Float16 f16x8 __attribute__((ext_vector_type(8)));
typedef float f32x4 __attribute__((ext_vector_type(4)));

__device__ __forceinline__ float lrelu(float x){ return x > 0.f ? x : NEG_SLOPE * x; }
__device__ __forceinline__ float eluf(float x){ return x > 0.f ? x : expm1f(x); }

// ---------------- CSR build (by dst) ----------------
__global__ void zero_int_kernel(int* __restrict__ p, int n){
  int i = blockIdx.x * blockDim.x + threadIdx.x;
  if (i < n) p[i] = 0;
}

__global__ void count_deg_kernel(const int* __restrict__ dst, int* __restrict__ deg, int E){
  int i = blockIdx.x * blockDim.x + threadIdx.x;
  if (i < E) atomicAdd(&deg[dst[i]], 1);
}

__global__ __launch_bounds__(256) void scan1_kernel(const int* __restrict__ deg,
    int* __restrict__ offsets, int* __restrict__ blockSums, int N){
  __shared__ int sm[256];
  int b = blockIdx.x, t = threadIdx.x;
  int i = b * 256 + t;
  int v = (i < N) ? deg[i] : 0;
  sm[t] = v;
  __syncthreads();
  #pragma unroll
  for (int st = 1; st < 256; st <<= 1){
    int add = (t >= st) ? sm[t - st] : 0;
    __syncthreads();
    sm[t] += add;
    __syncthreads();
  }
  if (i < N) offsets[i] = sm[t] - v;
  if (t == 255) blockSums[b] = sm[255];
}

__global__ __launch_bounds__(256) void scan2_kernel(const int* __restrict__ blockSums,
    int* __restrict__ blockBase, int* __restrict__ offsetsN, int nb){
  __shared__ int sm[256];
  int t = threadIdx.x;
  int v = (t < nb) ? blockSums[t] : 0;
  sm[t] = v;
  __syncthreads();
  #pragma unroll
  for (int st = 1; st < 256; st <<= 1){
    int add = (t >= st) ? sm[t - st] : 0;
    __syncthreads();
    sm[t] += add;
    __syncthreads();
  }
  if (t < nb) blockBase[t] = sm[t] - v;
  if (t == 255) *offsetsN = sm[255];
}

__global__ __launch_bounds__(256) void scan3_kernel(int* __restrict__ offsets,
    const int* __restrict__ blockBase, int* __restrict__ cursor, int N){
  int b = blockIdx.x, t = threadIdx.x;
  int i = b * 256 + t;
  if (i < N){
    int v = offsets[i] + blockBase[b];
    offsets[i] = v;
    cursor[i] = v;
  }
}

__global__ void scatter_kernel(const int* __restrict__ src, const int* __restrict__ dst,
                               int* __restrict__ cursor, int* __restrict__ csr_src,
                               int* __restrict__ csr_eid, int E){
  int i = blockIdx.x * blockDim.x + threadIdx.x;
  if (i < E){
    int d = dst[i];
    int p = atomicAdd(&cursor[d], 1);
    csr_src[p] = src[i];
    csr_eid[p] = i;
  }
}

// ---------------- input converts ----------------
__global__ void cvt_x_kernel(const float* __restrict__ x, __half* __restrict__ x16, int n4){
  int i = blockIdx.x * blockDim.x + threadIdx.x;
  if (i < n4){
    float4 v = *reinterpret_cast<const float4*>(&x[(size_t)i * 4]);
    __half2 h01 = __floats2half2_rn(v.x, v.y);
    __half2 h23 = __floats2half2_rn(v.z, v.w);
    uint2 pack;
    pack.x = *reinterpret_cast<unsigned int*>(&h01);
    pack.y = *reinterpret_cast<unsigned int*>(&h23);
    *reinterpret_cast<uint2*>(&x16[(size_t)i * 4]) = pack;
  }
}

__global__ void cvt_w1_kernel(const float* __restrict__ W1, __half* __restrict__ W1t){
  int i = blockIdx.x * blockDim.x + threadIdx.x;
  int k = i >> 8, c = i & 255;
  if (i < 128 * 256) W1t[(size_t)c * 128 + k] = __float2half(W1[(size_t)k * 256 + c]);
}

// W2 [256][32] fp32 -> W2t [32][256] fp16
__global__ void cvt_w2_kernel(const float* __restrict__ W2, __half* __restrict__ W2t){
  int i = blockIdx.x * blockDim.x + threadIdx.x;
  int k = i >> 5, c = i & 31;
  if (i < 256 * 32) W2t[(size_t)c * 256 + k] = __float2half(W2[(size_t)k * 32 + c]);
}

// ---------------- layer 1 GEMM via MFMA: h1 = x16 @ W1t ----------------
__global__ __launch_bounds__(256) void gemm1_kernel(const __half* __restrict__ x16,
    const __half* __restrict__ W1t, const float* __restrict__ att_src,
    const float* __restrict__ att_dst, __half* __restrict__ h1,
    float* __restrict__ a_src_f, float* __restrict__ a_dst_f, int N){
  __shared__ _Float16 As[128 * 136];
  __shared__ _Float16 Bs[64 * 136];
  int tid = threadIdx.x;
  int lane = tid & 63, wid = tid >> 6;
  int rowBase = blockIdx.x * 128;
  int head = blockIdx.y;
  int colBase = head * 64;

  #pragma unroll
  for (int it = 0; it < 8; ++it){
    int li = it * 256 + tid;
    int r = li >> 4, seg = li & 15;
    int grow = rowBase + r;
    f16x8 v = {};
    if (grow < N) v = *reinterpret_cast<const f16x8*>(&x16[(size_t)grow * 128 + seg * 8]);
    *reinterpret_cast<f16x8*>(&As[r * 136 + seg * 8]) = v;
  }
  #pragma unroll
  for (int it = 0; it < 4; ++it){
    int li = it * 256 + tid;
    int c = li >> 4, seg = li & 15;
    f16x8 v = *reinterpret_cast<const f16x8*>(&W1t[(size_t)(colBase + c) * 128 + seg * 8]);
    *reinterpret_cast<f16x8*>(&Bs[c * 136 + seg * 8]) = v;
  }
  __syncthreads();

  f32x4 acc[2][4] = {};
  int l15 = lane & 15, l4 = lane >> 4;
  #pragma unroll
  for (int ks = 0; ks < 4; ++ks){
    int kOff = ks * 32 + l4 * 8;
    f16x8 a0 = *reinterpret_cast<const f16x8*>(&As[(wid * 32 + l15) * 136 + kOff]);
    f16x8 a1 = *reinterpret_cast<const f16x8*>(&As[(wid * 32 + 16 + l15) * 136 + kOff]);
    #pragma unroll
    for (int cc = 0; cc < 4; ++cc){
      f16x8 b = *reinterpret_cast<const f16x8*>(&Bs[(cc * 16 + l15) * 136 + kOff]);
      acc[0][cc] = __builtin_amdgcn_mfma_f32_16x16x32_f16(a0, b, acc[0][cc], 0, 0, 0);
      acc[1][cc] = __builtin_amdgcn_mfma_f32_16x16x32_f16(a1, b, acc[1][cc], 0, 0, 0);
    }
  }

  #pragma unroll
  for (int rr = 0; rr < 2; ++rr){
    #pragma unroll
    for (int i = 0; i < 4; ++i){
      int row = rowBase + wid * 32 + rr * 16 + l4 * 4 + i;
      if (row < N){
        #pragma unroll
        for (int cc = 0; cc < 4; ++cc)
          h1[(size_t)row * 256 + colBase + cc * 16 + l15] = __float2half(acc[rr][cc][i]);
      }
    }
  }
  float sw[4], dw[4];
  #pragma unroll
  for (int cc = 0; cc < 4; ++cc){
    sw[cc] = att_src[colBase + cc * 16 + l15];
    dw[cc] = att_dst[colBase + cc * 16 + l15];
  }
  #pragma unroll
  for (int rr = 0; rr < 2; ++rr){
    #pragma unroll
    for (int i = 0; i < 4; ++i){
      float ts = 0.f, td = 0.f;
      #pragma unroll
      for (int cc = 0; cc < 4; ++cc){
        ts += acc[rr][cc][i] * sw[cc];
        td += acc[rr][cc][i] * dw[cc];
      }
      #pragma unroll
      for (int st = 8; st > 0; st >>= 1){
        ts += __shfl_xor(ts, st);
        td += __shfl_xor(td, st);
      }
      int row = rowBase + wid * 32 + rr * 16 + l4 * 4 + i;
      if (l15 == 0 && row < N){
        a_src_f[(size_t)row * 4 + head] = ts;
        a_dst_f[(size_t)row * 4 + head] = td;
      }
    }
  }
}

// ---------------- layer 1 node kernel ----------------
// R8 counters: VALUBusy 71% -- agg loop recomputed exp(lrelu()) redundantly in
// all 16 lanes/head + random a_src_f gather. Fix: pass 3 writes per-edge alphas
// to LDS (lane j owns slot j); agg reads them (broadcast, conflict-free).
// h1b stored fp16 (read only by gemm2's MFMA).
__global__ __launch_bounds__(256) void node1_kernel(
    const __half* __restrict__ h1, const float4* __restrict__ a_src,
    const float* __restrict__ a_src_f, const float4* __restrict__ a_dst,
    const int* __restrict__ offsets, const int* __restrict__ csr_src,
    const int* __restrict__ csr_eid, const float* __restrict__ bias,
    __half* __restrict__ h1b, float* __restrict__ alpha1_out, int N){
  __shared__ float al_lds[4][4][64];
  int gid = blockIdx.x * blockDim.x + threadIdx.x;
  int n = gid >> 6, lane = gid & 63, wid = (threadIdx.x >> 6) & 3;
  if (n >= N) return;
  int off = offsets[n];
  int deg = offsets[n + 1] - off;
  float4 ad = a_dst[n];
  bool have0 = (lane < deg);
  float4 e0 = make_float4(-INFINITY, -INFINITY, -INFINITY, -INFINITY);
  if (have0){
    float4 as = a_src[csr_src[off + lane]];
    e0 = make_float4(lrelu(as.x + ad.x), lrelu(as.y + ad.y),
                     lrelu(as.z + ad.z), lrelu(as.w + ad.w));
  }
  float m0 = e0.x, m1 = e0.y, m2 = e0.z, m3 = e0.w;
  for (int i = lane + 64; i < deg; i += 64){
    float4 as = a_src[csr_src[off + i]];
    m0 = fmaxf(m0, lrelu(as.x + ad.x));
    m1 = fmaxf(m1, lrelu(as.y + ad.y));
    m2 = fmaxf(m2, lrelu(as.z + ad.z));
    m3 = fmaxf(m3, lrelu(as.w + ad.w));
  }
  #pragma unroll
  for (int st = 32; st > 0; st >>= 1){
    m0 = fmaxf(m0, __shfl_xor(m0, st));
    m1 = fmaxf(m1, __shfl_xor(m1, st));
    m2 = fmaxf(m2, __shfl_xor(m2, st));
    m3 = fmaxf(m3, __shfl_xor(m3, st));
  }
  float s0 = 0.f, s1 = 0.f, s2 = 0.f, s3 = 0.f;
  if (have0){
    s0 = __expf(e0.x - m0); s1 = __expf(e0.y - m1);
    s2 = __expf(e0.z - m2); s3 = __expf(e0.w - m3);
  }
  for (int i = lane + 64; i < deg; i += 64){
    float4 as = a_src[csr_src[off + i]];
    s0 += __expf(lrelu(as.x + ad.x) - m0);
    s1 += __expf(lrelu(as.y + ad.y) - m1);
    s2 += __expf(lrelu(as.z + ad.z) - m2);
    s3 += __expf(lrelu(as.w + ad.w) - m3);
  }
  #pragma unroll
  for (int st = 32; st > 0; st >>= 1){
    s0 += __shfl_xor(s0, st); s1 += __shfl_xor(s1, st);
    s2 += __shfl_xor(s2, st); s3 += __shfl_xor(s3, st);
  }
  float i0 = 1.f / (s0 + EPS_C), i1 = 1.f / (s1 + EPS_C);
  float i2 = 1.f / (s2 + EPS_C), i3 = 1.f / (s3 + EPS_C);
  // pass 3: alpha write (global, original edge order) + LDS cache (slot order)
  if (have0){
    float a0 = __expf(e0.x - m0) * i0, a1 = __expf(e0.y - m1) * i1;
    float a2 = __expf(e0.z - m2) * i2, a3 = __expf(e0.w - m3) * i3;
    al_lds[wid][0][lane] = a0; al_lds[wid][1][lane] = a1;
    al_lds[wid][2][lane] = a2; al_lds[wid][3][lane] = a3;
    int eid = csr_eid[off + lane];
    *reinterpret_cast<float4*>(&alpha1_out[(size_t)eid * 4]) = make_float4(a0, a1, a2, a3);
  }
  for (int i = lane + 64; i < deg; i += 64){
    int slot = off + i;
    float4 as = a_src[csr_src[slot]];
    int eid = csr_eid[slot];
    *reinterpret_cast<float4*>(&alpha1_out[(size_t)eid * 4]) =
        make_float4(__expf(lrelu(as.x + ad.x) - m0) * i0,
                    __expf(lrelu(as.y + ad.y) - m1) * i1,
                    __expf(lrelu(as.z + ad.z) - m2) * i2,
                    __expf(lrelu(as.w + ad.w) - m3) * i3);
  }
  // aggregation: alphas from LDS for j<64; fallback recompute beyond.
  int head = lane >> 4;
  float mh  = head == 0 ? m0 : head == 1 ? m1 : head == 2 ? m2 : m3;
  float ih  = head == 0 ? i0 : head == 1 ? i1 : head == 2 ? i2 : i3;
  float adh = head == 0 ? ad.x : head == 1 ? ad.y : head == 2 ? ad.z : ad.w;
  float4 accA = make_float4(0.f, 0.f, 0.f, 0.f);
  float4 accB = make_float4(0.f, 0.f, 0.f, 0.f);
  float4 accC = make_float4(0.f, 0.f, 0.f, 0.f);
  float4 accD = make_float4(0.f, 0.f, 0.f, 0.f);
  int degL = deg < 64 ? deg : 64;
  int j = 0;
  for (; j + 3 < degL; j += 4){
    int sA = csr_src[off + j];
    int sB = csr_src[off + j + 1];
    int sC = csr_src[off + j + 2];
    int sD = csr_src[off + j + 3];
    float alA = al_lds[wid][head][j];
    float alB = al_lds[wid][head][j + 1];
    float alC = al_lds[wid][head][j + 2];
    float alD = al_lds[wid][head][j + 3];
    float2 rA = *reinterpret_cast<const float2*>(&h1[(size_t)sA * 256 + lane * 4]);
    float2 rB = *reinterpret_cast<const float2*>(&h1[(size_t)sB * 256 + lane * 4]);
    float2 rC = *reinterpret_cast<const float2*>(&h1[(size_t)sC * 256 + lane * 4]);
    float2 rD = *reinterpret_cast<const float2*>(&h1[(size_t)sD * 256 + lane * 4]);
    float2 fA0 = __half22float2(*reinterpret_cast<__half2*>(&rA.x));
    float2 fA1 = __half22float2(*reinterpret_cast<__half2*>(&rA.y));
    float2 fB0 = __half22float2(*reinterpret_cast<__half2*>(&rB.x));
    float2 fB1 = __half22float2(*reinterpret_cast<__half2*>(&rB.y));
    float2 fC0 = __half22float2(*reinterpret_cast<__half2*>(&rC.x));
    float2 fC1 = __half22float2(*reinterpret_cast<__half2*>(&rC.y));
    float2 fD0 = __half22float2(*reinterpret_cast<__half2*>(&rD.x));
    float2 fD1 = __half22float2(*reinterpret_cast<__half2*>(&rD.y));
    accA.x += alA * fA0.x; accA.y += alA * fA0.y; accA.z += alA * fA1.x; accA.w += alA * fA1.y;
    accB.x += alB * fB0.x; accB.y += alB * fB0.y; accB.z += alB * fB1.x; accB.w += alB * fB1.y;
    accC.x += alC * fC0.x; accC.y += alC * fC0.y; accC.z += alC * fC1.x; accC.w += alC * fC1.y;
    accD.x += alD * fD0.x; accD.y += alD * fD0.y; accD.z += alD * fD1.x; accD.w += alD * fD1.y;
  }
  for (; j < degL; ++j){
    int sA = csr_src[off + j];
    float alA = al_lds[wid][head][j];
    float2 rA = *reinterpret_cast<const float2*>(&h1[(size_t)sA * 256 + lane * 4]);
    float2 fA0 = __half22float2(*reinterpret_cast<__half2*>(&rA.x));
    float2 fA1 = __half22float2(*reinterpret_cast<__half2*>(&rA.y));
    accA.x += alA * fA0.x; accA.y += alA * fA0.y; accA.z += alA * fA1.x; accA.w += alA * fA1.y;
  }
  for (; j < deg; ++j){   // rare deg>64 tail
    int sA = csr_src[off + j];
    float alA = __expf(lrelu(a_src_f[(size_t)sA * 4 + head] + adh) - mh) * ih;
    float2 rA = *reinterpret_cast<const float2*>(&h1[(size_t)sA * 256 + lane * 4]);
    float2 fA0 = __half22float2(*reinterpret_cast<__half2*>(&rA.x));
    float2 fA1 = __half22float2(*reinterpret_cast<__half2*>(&rA.y));
    accA.x += alA * fA0.x; accA.y += alA * fA0.y; accA.z += alA * fA1.x; accA.w += alA * fA1.y;
  }
  accA.x += accB.x + accC.x + accD.x;
  accA.y += accB.y + accC.y + accD.y;
  accA.z += accB.z + accC.z + accD.z;
  accA.w += accB.w + accC.w + accD.w;
  float4 b = *reinterpret_cast<const float4*>(&bias[lane * 4]);
  __half2 o01 = __floats2half2_rn(eluf(accA.x + b.x), eluf(accA.y + b.y));
  __half2 o23 = __floats2half2_rn(eluf(accA.z + b.z), eluf(accA.w + b.w));
  uint2 pack;
  pack.x = *reinterpret_cast<unsigned int*>(&o01);
  pack.y = *reinterpret_cast<unsigned int*>(&o23);
  *reinterpret_cast<uint2*>(&h1b[(size_t)n * 256 + lane * 4]) = pack;
}

// ---------------- layer 2 GEMM via MFMA: h2pre = h1b16 @ W2t [N,256]x[256,32] ----
__global__ __launch_bounds__(256) void gemm2_kernel(const __half* __restrict__ h1b,
    const __half* __restrict__ W2t, const float* __restrict__ att_src2,
    const float* __restrict__ att_dst2, __half* __restrict__ h2pre,
    float* __restrict__ a_src2, float* __restrict__ a_dst2, int N){
  __shared__ _Float16 As[128 * 136];
  __shared__ _Float16 Bs[32 * 136];
  int tid = threadIdx.x;
  int lane = tid & 63, wid = tid >> 6;
  int rowBase = blockIdx.x * 128;
  int l15 = lane & 15, l4 = lane >> 4;
  f32x4 acc[2][2] = {};

  for (int kc = 0; kc < 2; ++kc){
    if (kc) __syncthreads();
    #pragma unroll
    for (int it = 0; it < 8; ++it){
      int li = it * 256 + tid;
      int r = li >> 4, seg = li & 15;
      int grow = rowBase + r;
      f16x8 v = {};
      if (grow < N) v = *reinterpret_cast<const f16x8*>(&h1b[(size_t)grow * 256 + kc * 128 + seg * 8]);
      *reinterpret_cast<f16x8*>(&As[r * 136 + seg * 8]) = v;
    }
    #pragma unroll
    for (int it = 0; it < 2; ++it){
      int li = it * 256 + tid;
      int c = li >> 4, seg = li & 15;
      f16x8 v = *reinterpret_cast<const f16x8*>(&W2t[(size_t)c * 256 + kc * 128 + seg * 8]);
      *reinterpret_cast<f16x8*>(&Bs[c * 136 + seg * 8]) = v;
    }
    __syncthreads();
    #pragma unroll
    for (int ks = 0; ks < 4; ++ks){
      int kOff = ks * 32 + l4 * 8;
      f16x8 a0 = *reinterpret_cast<const f16x8*>(&As[(wid * 32 + l15) * 136 + kOff]);
      f16x8 a1 = *reinterpret_cast<const f16x8*>(&As[(wid * 32 + 16 + l15) * 136 + kOff]);
      #pragma unroll
      for (int cb = 0; cb < 2; ++cb){
        f16x8 b = *reinterpret_cast<const f16x8*>(&Bs[(cb * 16 + l15) * 136 + kOff]);
        acc[0][cb] = __builtin_amdgcn_mfma_f32_16x16x32_f16(a0, b, acc[0][cb], 0, 0, 0);
        acc[1][cb] = __builtin_amdgcn_mfma_f32_16x16x32_f16(a1, b, acc[1][cb], 0, 0, 0);
      }
    }
  }
  // store h2pre fp16 + fused att2 dots
  #pragma unroll
  for (int rr = 0; rr < 2; ++rr){
    #pragma unroll
    for (int i = 0; i < 4; ++i){
      int row = rowBase + wid * 32 + rr * 16 + l4 * 4 + i;
      if (row < N){
        #pragma unroll
        for (int cb = 0; cb < 2; ++cb)
          h2pre[(size_t)row * 32 + cb * 16 + l15] = __float2half(acc[rr][cb][i]);
      }
    }
  }
  float sw0 = att_src2[l15], sw1 = att_src2[16 + l15];
  float dw0 = att_dst2[l15], dw1 = att_dst2[16 + l15];
  #pragma unroll
  for (int rr = 0; rr < 2; ++rr){
    #pragma unroll
    for (int i = 0; i < 4; ++i){
      float ts = acc[rr][0][i] * sw0 + acc[rr][1][i] * sw1;
      float td = acc[rr][0][i] * dw0 + acc[rr][1][i] * dw1;
      #pragma unroll
      for (int st = 8; st > 0; st >>= 1){
        ts += __shfl_xor(ts, st);
        td += __shfl_xor(td, st);
      }
      int row = rowBase + wid * 32 + rr * 16 + l4 * 4 + i;
      if (l15 == 0 && row < N){
        a_src2[row] = ts;
        a_dst2[row] = td;
      }
    }
  }
}

// ---------------- layer 2 node kernel ----------------
__global__ __launch_bounds__(256) void node2_kernel(
    const __half* __restrict__ h2pre, const float* __restrict__ a_src2,
    const float* __restrict__ a_dst2, const int* __restrict__ offsets,
    const int* __restrict__ csr_src, const int* __restrict__ csr_eid,
    const float* __restrict__ bias2, float* __restrict__ out_h2,
    float* __restrict__ alpha2_out, int N){
  __shared__ float al_lds[4][64];
  int gid = blockIdx.x * blockDim.x + threadIdx.x;
  int n = gid >> 6, lane = gid & 63, wid = (threadIdx.x >> 6) & 3;
  if (n >= N) return;
  int off = offsets[n], deg = offsets[n + 1] - off;
  float adn = a_dst2[n];
  bool have0 = (lane < deg);
  float e0 = -INFINITY;
  if (have0) e0 = lrelu(a_src2[csr_src[off + lane]] + adn);
  float m = e0;
  for (int i = lane + 64; i < deg; i += 64)
    m = fmaxf(m, lrelu(a_src2[csr_src[off + i]] + adn));
  #pragma unroll
  for (int st = 32; st > 0; st >>= 1) m = fmaxf(m, __shfl_xor(m, st));
  float s = have0 ? __expf(e0 - m) : 0.f;
  for (int i = lane + 64; i < deg; i += 64)
    s += __expf(lrelu(a_src2[csr_src[off + i]] + adn) - m);
  #pragma unroll
  for (int st = 32; st > 0; st >>= 1) s += __shfl_xor(s, st);
  float inv = 1.f / (s + EPS_C);
  if (have0){
    float al = __expf(e0 - m) * inv;
    al_lds[wid][lane] = al;
    alpha2_out[csr_eid[off + lane]] = al;
  }
  for (int i = lane + 64; i < deg; i += 64){
    int slot = off + i;
    alpha2_out[csr_eid[slot]] = __expf(lrelu(a_src2[csr_src[slot]] + adn) - m) * inv;
  }
  int c = lane & 31, half = lane >> 5;
  int degL = deg < 64 ? deg : 64;
  float acc = 0.f;
  int j = half;
  for (; j < degL; j += 2){
    int src = csr_src[off + j];
    acc += al_lds[wid][j] * __half2float(h2pre[(size_t)src * 32 + c]);
  }
  for (; j < deg; j += 2){   // rare deg>64 tail
    int src = csr_src[off + j];
    float al = __expf(lrelu(a_src2[src] + adn) - m) * inv;
    acc += al * __half2float(h2pre[(size_t)src * 32 + c]);
  }
  acc += __shfl_xor(acc, 32);
  if (lane < 32) out_h2[(size_t)n * 32 + c] = acc + bias2[c];
}

// ---------------- echo edge_index ----------------
__global__ void edge_out_kernel(const int* __restrict__ ei, float* __restrict__ out1,
                                float* __restrict__ out3, int n2e){
  int i = blockIdx.x * blockDim.x + threadIdx.x;
  if (i < n2e){
    float v = (float)ei[i];
    out1[i] = v; out3[i] = v;
  }
}

extern "C" void kernel_launch(void* const* d_in, const int* in_sizes, int n_in,
                              void* d_out, int out_size, void* d_ws, size_t ws_size,
                              hipStream_t stream){
  const float* x        = (const float*)d_in[0];
  const int*   ei       = (const int*)d_in[1];
  const float* W1       = (const float*)d_in[2];
  const float* att_src1 = (const float*)d_in[3];
  const float* att_dst1 = (const float*)d_in[4];
  const float* bias1    = (const float*)d_in[5];
  const float* W2       = (const float*)d_in[6];
  const float* att_src2 = (const float*)d_in[7];
  const float* att_dst2 = (const float*)d_in[8];
  const float* bias2    = (const float*)d_in[9];
  float* out = (float*)d_out;
  (void)n_in; (void)out_size; (void)ws_size;

  const int N = in_sizes[0] / 128;
  const int E = in_sizes[1] / 2;
  const int* src = ei;
  const int* dst = ei + E;
  const int nb = (N + 255) / 256;

  char* ws = (char*)d_ws;
  size_t o = 0;
  auto alloc = [&](size_t bytes) -> void* {
    void* p = ws + o;
    o += (bytes + 255) & ~(size_t)255;
    return p;
  };
  __half* h1      = (__half*)alloc((size_t)N * 256 * 2);
  __half* x16     = (__half*)alloc((size_t)N * 128 * 2);
  __half* W1t     = (__half*)alloc((size_t)256 * 128 * 2);
  __half* W2t     = (__half*)alloc((size_t)32 * 256 * 2);
  __half* h1b     = (__half*)alloc((size_t)N * 256 * 2);
  __half* h2pre   = (__half*)alloc((size_t)N * 32 * 2);
  float*  a_src1  = (float*)alloc((size_t)N * 16);
  float*  a_dst1  = (float*)alloc((size_t)N * 16);
  float*  a_src2  = (float*)alloc((size_t)N * 4);
  float*  a_dst2  = (float*)alloc((size_t)N * 4);
  int*    deg     = (int*)alloc((size_t)N * 4);
  int*    offsets = (int*)alloc((size_t)(N + 1) * 4);
  int*    cursor  = (int*)alloc((size_t)N * 4);
  int*    csr_src = (int*)alloc((size_t)E * 4);
  int*    csr_eid = (int*)alloc((size_t)E * 4);
  int*    blockSums = (int*)alloc(256 * 4);
  int*    blockBase = (int*)alloc(256 * 4);

  const size_t OFF1 = (size_t)N * 32;
  const size_t OFF2 = OFF1 + (size_t)2 * E;
  const size_t OFF3 = OFF2 + (size_t)E * 4;
  const size_t OFF4 = OFF3 + (size_t)2 * E;

  int n4 = (N * 128) / 4;
  hipLaunchKernelGGL(cvt_x_kernel, dim3((n4 + 255) / 256), dim3(256), 0, stream, x, x16, n4);
  hipLaunchKernelGGL(cvt_w1_kernel, dim3(128), dim3(256), 0, stream, W1, W1t);
  hipLaunchKernelGGL(cvt_w2_kernel, dim3(32), dim3(256), 0, stream, W2, W2t);
  hipLaunchKernelGGL(zero_int_kernel, dim3((N + 255) / 256), dim3(256), 0, stream, deg, N);
  hipLaunchKernelGGL(count_deg_kernel, dim3((E + 255) / 256), dim3(256), 0, stream, dst, deg, E);
  hipLaunchKernelGGL(scan1_kernel, dim3(nb), dim3(256), 0, stream, deg, offsets, blockSums, N);
  hipLaunchKernelGGL(scan2_kernel, dim3(1), dim3(256), 0, stream, blockSums, blockBase,
                     offsets + N, nb);
  hipLaunchKernelGGL(scan3_kernel, dim3(nb), dim3(256), 0, stream, offsets, blockBase, cursor, N);
  hipLaunchKernelGGL(scatter_kernel, dim3((E + 255) / 256), dim3(256), 0, stream,
                     src, dst, cursor, csr_src, csr_eid, E);
  hipLaunchKernelGGL(gemm1_kernel, dim3((N + 127) / 128, 4), dim3(256), 0, stream,
                     x16, W1t, att_src1, att_dst1, h1, a_src1, a_dst1, N);
  hipLaunchKernelGGL(node1_kernel, dim3((N * 64 + 255) / 256), dim3(256), 0, stream,
                     h1, (const float4*)a_src1, (const float*)a_src1, (const float4*)a_dst1,
                     offsets, csr_src, csr_eid, bias1, h1b, out + OFF2, N);
  hipLaunchKernelGGL(gemm2_kernel, dim3((N + 127) / 128), dim3(256), 0, stream,
                     h1b, W2t, att_src2, att_dst2, h2pre, a_src2, a_dst2, N);
  hipLaunchKernelGGL(node2_kernel, dim3((N * 64 + 255) / 256), dim3(256), 0, stream,
                     h2pre, a_src2, a_dst2, offsets, csr_src, csr_eid, bias2,
                     out, out + OFF4, N);
  hipLaunchKernelGGL(edge_out_kernel, dim3((2 * E + 255) / 256), dim3(256), 0, stream,
                     ei, out + OFF1, out + OFF3, 2 * E);
}

// Round 11
// 348.581 us; speedup vs baseline: 1.9674x; 1.0368x over previous
//
#include <hip/hip_runtime.h>
#include <hip/hip_fp16.h>
#include <math.h>

#define NEG_SLOPE 0.2f
#define EPS_C 1e-16f

typedef _Float16 f16x8 __attribute__((ext_vector_type(8)));
typedef float f32x4 __attribute__((ext_vector_type(4)));

__device__ __forceinline__ float lrelu(float x){ return x > 0.f ? x : NEG_SLOPE * x; }
__device__ __forceinline__ float eluf(float x){ return x > 0.f ? x : expm1f(x); }

// ---------------- fused prep: x->fp16 | W1->fp16^T | W2->fp16^T | deg=0 ----------------
// R10: tail was ~14 dispatches; fuse the 4 tiny prologue kernels into one
// range-partitioned launch (saves ~3 launches of overhead).
__global__ void prep_kernel(const float* __restrict__ x, __half* __restrict__ x16,
                            const float* __restrict__ W1, __half* __restrict__ W1t,
                            const float* __restrict__ W2, __half* __restrict__ W2t,
                            int* __restrict__ deg, int n4, int N){
  int i = blockIdx.x * blockDim.x + threadIdx.x;
  if (i < n4){
    float4 v = *reinterpret_cast<const float4*>(&x[(size_t)i * 4]);
    __half2 h01 = __floats2half2_rn(v.x, v.y);
    __half2 h23 = __floats2half2_rn(v.z, v.w);
    uint2 pack;
    pack.x = *reinterpret_cast<unsigned int*>(&h01);
    pack.y = *reinterpret_cast<unsigned int*>(&h23);
    *reinterpret_cast<uint2*>(&x16[(size_t)i * 4]) = pack;
    return;
  }
  int j = i - n4;
  if (j < 128 * 256){
    int k = j >> 8, c = j & 255;
    W1t[(size_t)c * 128 + k] = __float2half(W1[(size_t)k * 256 + c]);
    return;
  }
  j -= 128 * 256;
  if (j < 256 * 32){
    int k = j >> 5, c = j & 31;
    W2t[(size_t)c * 256 + k] = __float2half(W2[(size_t)k * 32 + c]);
    return;
  }
  j -= 256 * 32;
  if (j < N) deg[j] = 0;
}

// ---------------- fused: edge echo + degree count (single pass over ei) ----------------
__global__ void edge_deg_kernel(const int* __restrict__ ei, float* __restrict__ out1,
                                float* __restrict__ out3, int* __restrict__ deg,
                                int E, int n2e){
  int i = blockIdx.x * blockDim.x + threadIdx.x;
  if (i < n2e){
    int v = ei[i];
    float f = (float)v;
    out1[i] = f; out3[i] = f;
    if (i >= E) atomicAdd(&deg[v], 1);   // ei[E..2E) == dst
  }
}

__global__ __launch_bounds__(256) void scan1_kernel(const int* __restrict__ deg,
    int* __restrict__ offsets, int* __restrict__ blockSums, int N){
  __shared__ int sm[256];
  int b = blockIdx.x, t = threadIdx.x;
  int i = b * 256 + t;
  int v = (i < N) ? deg[i] : 0;
  sm[t] = v;
  __syncthreads();
  #pragma unroll
  for (int st = 1; st < 256; st <<= 1){
    int add = (t >= st) ? sm[t - st] : 0;
    __syncthreads();
    sm[t] += add;
    __syncthreads();
  }
  if (i < N) offsets[i] = sm[t] - v;
  if (t == 255) blockSums[b] = sm[255];
}

__global__ __launch_bounds__(256) void scan2_kernel(const int* __restrict__ blockSums,
    int* __restrict__ blockBase, int* __restrict__ offsetsN, int nb){
  __shared__ int sm[256];
  int t = threadIdx.x;
  int v = (t < nb) ? blockSums[t] : 0;
  sm[t] = v;
  __syncthreads();
  #pragma unroll
  for (int st = 1; st < 256; st <<= 1){
    int add = (t >= st) ? sm[t - st] : 0;
    __syncthreads();
    sm[t] += add;
    __syncthreads();
  }
  if (t < nb) blockBase[t] = sm[t] - v;
  if (t == 255) *offsetsN = sm[255];
}

__global__ __launch_bounds__(256) void scan3_kernel(int* __restrict__ offsets,
    const int* __restrict__ blockBase, int* __restrict__ cursor, int N){
  int b = blockIdx.x, t = threadIdx.x;
  int i = b * 256 + t;
  if (i < N){
    int v = offsets[i] + blockBase[b];
    offsets[i] = v;
    cursor[i] = v;
  }
}

__global__ void scatter_kernel(const int* __restrict__ src, const int* __restrict__ dst,
                               int* __restrict__ cursor, int* __restrict__ csr_src,
                               int* __restrict__ csr_eid, int E){
  int i = blockIdx.x * blockDim.x + threadIdx.x;
  if (i < E){
    int d = dst[i];
    int p = atomicAdd(&cursor[d], 1);
    csr_src[p] = src[i];
    csr_eid[p] = i;
  }
}

// ---------------- layer 1 GEMM via MFMA: h1 = x16 @ W1t ----------------
__global__ __launch_bounds__(256) void gemm1_kernel(const __half* __restrict__ x16,
    const __half* __restrict__ W1t, const float* __restrict__ att_src,
    const float* __restrict__ att_dst, __half* __restrict__ h1,
    float* __restrict__ a_src_f, float* __restrict__ a_dst_f, int N){
  __shared__ _Float16 As[128 * 136];
  __shared__ _Float16 Bs[64 * 136];
  int tid = threadIdx.x;
  int lane = tid & 63, wid = tid >> 6;
  int rowBase = blockIdx.x * 128;
  int head = blockIdx.y;
  int colBase = head * 64;

  #pragma unroll
  for (int it = 0; it < 8; ++it){
    int li = it * 256 + tid;
    int r = li >> 4, seg = li & 15;
    int grow = rowBase + r;
    f16x8 v = {};
    if (grow < N) v = *reinterpret_cast<const f16x8*>(&x16[(size_t)grow * 128 + seg * 8]);
    *reinterpret_cast<f16x8*>(&As[r * 136 + seg * 8]) = v;
  }
  #pragma unroll
  for (int it = 0; it < 4; ++it){
    int li = it * 256 + tid;
    int c = li >> 4, seg = li & 15;
    f16x8 v = *reinterpret_cast<const f16x8*>(&W1t[(size_t)(colBase + c) * 128 + seg * 8]);
    *reinterpret_cast<f16x8*>(&Bs[c * 136 + seg * 8]) = v;
  }
  __syncthreads();

  f32x4 acc[2][4] = {};
  int l15 = lane & 15, l4 = lane >> 4;
  #pragma unroll
  for (int ks = 0; ks < 4; ++ks){
    int kOff = ks * 32 + l4 * 8;
    f16x8 a0 = *reinterpret_cast<const f16x8*>(&As[(wid * 32 + l15) * 136 + kOff]);
    f16x8 a1 = *reinterpret_cast<const f16x8*>(&As[(wid * 32 + 16 + l15) * 136 + kOff]);
    #pragma unroll
    for (int cc = 0; cc < 4; ++cc){
      f16x8 b = *reinterpret_cast<const f16x8*>(&Bs[(cc * 16 + l15) * 136 + kOff]);
      acc[0][cc] = __builtin_amdgcn_mfma_f32_16x16x32_f16(a0, b, acc[0][cc], 0, 0, 0);
      acc[1][cc] = __builtin_amdgcn_mfma_f32_16x16x32_f16(a1, b, acc[1][cc], 0, 0, 0);
    }
  }

  #pragma unroll
  for (int rr = 0; rr < 2; ++rr){
    #pragma unroll
    for (int i = 0; i < 4; ++i){
      int row = rowBase + wid * 32 + rr * 16 + l4 * 4 + i;
      if (row < N){
        #pragma unroll
        for (int cc = 0; cc < 4; ++cc)
          h1[(size_t)row * 256 + colBase + cc * 16 + l15] = __float2half(acc[rr][cc][i]);
      }
    }
  }
  float sw[4], dw[4];
  #pragma unroll
  for (int cc = 0; cc < 4; ++cc){
    sw[cc] = att_src[colBase + cc * 16 + l15];
    dw[cc] = att_dst[colBase + cc * 16 + l15];
  }
  #pragma unroll
  for (int rr = 0; rr < 2; ++rr){
    #pragma unroll
    for (int i = 0; i < 4; ++i){
      float ts = 0.f, td = 0.f;
      #pragma unroll
      for (int cc = 0; cc < 4; ++cc){
        ts += acc[rr][cc][i] * sw[cc];
        td += acc[rr][cc][i] * dw[cc];
      }
      #pragma unroll
      for (int st = 8; st > 0; st >>= 1){
        ts += __shfl_xor(ts, st);
        td += __shfl_xor(td, st);
      }
      int row = rowBase + wid * 32 + rr * 16 + l4 * 4 + i;
      if (l15 == 0 && row < N){
        a_src_f[(size_t)row * 4 + head] = ts;
        a_dst_f[(size_t)row * 4 + head] = td;
      }
    }
  }
}

// ---------------- layer 1 node kernel ----------------
// R10 counters: 82us, VALU 57%, hbm 40%, occ 65% -- no pipe saturated =>
// residual latency in the serial gather chain. MLP 4 -> 8 (two 8-deep
// batches for deg~16 instead of four 4-deep).
__global__ __launch_bounds__(256) void node1_kernel(
    const __half* __restrict__ h1, const float4* __restrict__ a_src,
    const float* __restrict__ a_src_f, const float4* __restrict__ a_dst,
    const int* __restrict__ offsets, const int* __restrict__ csr_src,
    const int* __restrict__ csr_eid, const float* __restrict__ bias,
    __half* __restrict__ h1b, float* __restrict__ alpha1_out, int N){
  __shared__ float al_lds[4][4][64];
  int gid = blockIdx.x * blockDim.x + threadIdx.x;
  int n = gid >> 6, lane = gid & 63, wid = (threadIdx.x >> 6) & 3;
  if (n >= N) return;
  int off = offsets[n];
  int deg = offsets[n + 1] - off;
  float4 ad = a_dst[n];
  bool have0 = (lane < deg);
  float4 e0 = make_float4(-INFINITY, -INFINITY, -INFINITY, -INFINITY);
  if (have0){
    float4 as = a_src[csr_src[off + lane]];
    e0 = make_float4(lrelu(as.x + ad.x), lrelu(as.y + ad.y),
                     lrelu(as.z + ad.z), lrelu(as.w + ad.w));
  }
  float m0 = e0.x, m1 = e0.y, m2 = e0.z, m3 = e0.w;
  for (int i = lane + 64; i < deg; i += 64){
    float4 as = a_src[csr_src[off + i]];
    m0 = fmaxf(m0, lrelu(as.x + ad.x));
    m1 = fmaxf(m1, lrelu(as.y + ad.y));
    m2 = fmaxf(m2, lrelu(as.z + ad.z));
    m3 = fmaxf(m3, lrelu(as.w + ad.w));
  }
  #pragma unroll
  for (int st = 32; st > 0; st >>= 1){
    m0 = fmaxf(m0, __shfl_xor(m0, st));
    m1 = fmaxf(m1, __shfl_xor(m1, st));
    m2 = fmaxf(m2, __shfl_xor(m2, st));
    m3 = fmaxf(m3, __shfl_xor(m3, st));
  }
  float s0 = 0.f, s1 = 0.f, s2 = 0.f, s3 = 0.f;
  if (have0){
    s0 = __expf(e0.x - m0); s1 = __expf(e0.y - m1);
    s2 = __expf(e0.z - m2); s3 = __expf(e0.w - m3);
  }
  for (int i = lane + 64; i < deg; i += 64){
    float4 as = a_src[csr_src[off + i]];
    s0 += __expf(lrelu(as.x + ad.x) - m0);
    s1 += __expf(lrelu(as.y + ad.y) - m1);
    s2 += __expf(lrelu(as.z + ad.z) - m2);
    s3 += __expf(lrelu(as.w + ad.w) - m3);
  }
  #pragma unroll
  for (int st = 32; st > 0; st >>= 1){
    s0 += __shfl_xor(s0, st); s1 += __shfl_xor(s1, st);
    s2 += __shfl_xor(s2, st); s3 += __shfl_xor(s3, st);
  }
  float i0 = 1.f / (s0 + EPS_C), i1 = 1.f / (s1 + EPS_C);
  float i2 = 1.f / (s2 + EPS_C), i3 = 1.f / (s3 + EPS_C);
  if (have0){
    float a0 = __expf(e0.x - m0) * i0, a1 = __expf(e0.y - m1) * i1;
    float a2 = __expf(e0.z - m2) * i2, a3 = __expf(e0.w - m3) * i3;
    al_lds[wid][0][lane] = a0; al_lds[wid][1][lane] = a1;
    al_lds[wid][2][lane] = a2; al_lds[wid][3][lane] = a3;
    int eid = csr_eid[off + lane];
    *reinterpret_cast<float4*>(&alpha1_out[(size_t)eid * 4]) = make_float4(a0, a1, a2, a3);
  }
  for (int i = lane + 64; i < deg; i += 64){
    int slot = off + i;
    float4 as = a_src[csr_src[slot]];
    int eid = csr_eid[slot];
    *reinterpret_cast<float4*>(&alpha1_out[(size_t)eid * 4]) =
        make_float4(__expf(lrelu(as.x + ad.x) - m0) * i0,
                    __expf(lrelu(as.y + ad.y) - m1) * i1,
                    __expf(lrelu(as.z + ad.z) - m2) * i2,
                    __expf(lrelu(as.w + ad.w) - m3) * i3);
  }
  // aggregation: MLP 8 with LDS alphas (j<64); fallback recompute beyond.
  int head = lane >> 4;
  float mh  = head == 0 ? m0 : head == 1 ? m1 : head == 2 ? m2 : m3;
  float ih  = head == 0 ? i0 : head == 1 ? i1 : head == 2 ? i2 : i3;
  float adh = head == 0 ? ad.x : head == 1 ? ad.y : head == 2 ? ad.z : ad.w;
  float4 acc[8];
  #pragma unroll
  for (int u = 0; u < 8; ++u) acc[u] = make_float4(0.f, 0.f, 0.f, 0.f);
  int degL = deg < 64 ? deg : 64;
  int j = 0;
  for (; j + 7 < degL; j += 8){
    int s[8];
    #pragma unroll
    for (int u = 0; u < 8; ++u) s[u] = csr_src[off + j + u];
    float2 r[8];
    #pragma unroll
    for (int u = 0; u < 8; ++u)
      r[u] = *reinterpret_cast<const float2*>(&h1[(size_t)s[u] * 256 + lane * 4]);
    #pragma unroll
    for (int u = 0; u < 8; ++u){
      float al = al_lds[wid][head][j + u];
      float2 f0 = __half22float2(*reinterpret_cast<__half2*>(&r[u].x));
      float2 f1 = __half22float2(*reinterpret_cast<__half2*>(&r[u].y));
      acc[u].x += al * f0.x; acc[u].y += al * f0.y;
      acc[u].z += al * f1.x; acc[u].w += al * f1.y;
    }
  }
  for (; j < degL; ++j){
    int sA = csr_src[off + j];
    float al = al_lds[wid][head][j];
    float2 rA = *reinterpret_cast<const float2*>(&h1[(size_t)sA * 256 + lane * 4]);
    float2 f0 = __half22float2(*reinterpret_cast<__half2*>(&rA.x));
    float2 f1 = __half22float2(*reinterpret_cast<__half2*>(&rA.y));
    acc[0].x += al * f0.x; acc[0].y += al * f0.y;
    acc[0].z += al * f1.x; acc[0].w += al * f1.y;
  }
  for (; j < deg; ++j){   // rare deg>64 tail
    int sA = csr_src[off + j];
    float al = __expf(lrelu(a_src_f[(size_t)sA * 4 + head] + adh) - mh) * ih;
    float2 rA = *reinterpret_cast<const float2*>(&h1[(size_t)sA * 256 + lane * 4]);
    float2 f0 = __half22float2(*reinterpret_cast<__half2*>(&rA.x));
    float2 f1 = __half22float2(*reinterpret_cast<__half2*>(&rA.y));
    acc[0].x += al * f0.x; acc[0].y += al * f0.y;
    acc[0].z += al * f1.x; acc[0].w += al * f1.y;
  }
  #pragma unroll
  for (int u = 1; u < 8; ++u){
    acc[0].x += acc[u].x; acc[0].y += acc[u].y;
    acc[0].z += acc[u].z; acc[0].w += acc[u].w;
  }
  float4 b = *reinterpret_cast<const float4*>(&bias[lane * 4]);
  __half2 o01 = __floats2half2_rn(eluf(acc[0].x + b.x), eluf(acc[0].y + b.y));
  __half2 o23 = __floats2half2_rn(eluf(acc[0].z + b.z), eluf(acc[0].w + b.w));
  uint2 pack;
  pack.x = *reinterpret_cast<unsigned int*>(&o01);
  pack.y = *reinterpret_cast<unsigned int*>(&o23);
  *reinterpret_cast<uint2*>(&h1b[(size_t)n * 256 + lane * 4]) = pack;
}

// ---------------- layer 2 GEMM via MFMA: h2pre = h1b16 @ W2t ----------------
__global__ __launch_bounds__(256) void gemm2_kernel(const __half* __restrict__ h1b,
    const __half* __restrict__ W2t, const float* __restrict__ att_src2,
    const float* __restrict__ att_dst2, __half* __restrict__ h2pre,
    float* __restrict__ a_src2, float* __restrict__ a_dst2, int N){
  __shared__ _Float16 As[128 * 136];
  __shared__ _Float16 Bs[32 * 136];
  int tid = threadIdx.x;
  int lane = tid & 63, wid = tid >> 6;
  int rowBase = blockIdx.x * 128;
  int l15 = lane & 15, l4 = lane >> 4;
  f32x4 acc[2][2] = {};

  for (int kc = 0; kc < 2; ++kc){
    if (kc) __syncthreads();
    #pragma unroll
    for (int it = 0; it < 8; ++it){
      int li = it * 256 + tid;
      int r = li >> 4, seg = li & 15;
      int grow = rowBase + r;
      f16x8 v = {};
      if (grow < N) v = *reinterpret_cast<const f16x8*>(&h1b[(size_t)grow * 256 + kc * 128 + seg * 8]);
      *reinterpret_cast<f16x8*>(&As[r * 136 + seg * 8]) = v;
    }
    #pragma unroll
    for (int it = 0; it < 2; ++it){
      int li = it * 256 + tid;
      int c = li >> 4, seg = li & 15;
      f16x8 v = *reinterpret_cast<const f16x8*>(&W2t[(size_t)c * 256 + kc * 128 + seg * 8]);
      *reinterpret_cast<f16x8*>(&Bs[c * 136 + seg * 8]) = v;
    }
    __syncthreads();
    #pragma unroll
    for (int ks = 0; ks < 4; ++ks){
      int kOff = ks * 32 + l4 * 8;
      f16x8 a0 = *reinterpret_cast<const f16x8*>(&As[(wid * 32 + l15) * 136 + kOff]);
      f16x8 a1 = *reinterpret_cast<const f16x8*>(&As[(wid * 32 + 16 + l15) * 136 + kOff]);
      #pragma unroll
      for (int cb = 0; cb < 2; ++cb){
        f16x8 b = *reinterpret_cast<const f16x8*>(&Bs[(cb * 16 + l15) * 136 + kOff]);
        acc[0][cb] = __builtin_amdgcn_mfma_f32_16x16x32_f16(a0, b, acc[0][cb], 0, 0, 0);
        acc[1][cb] = __builtin_amdgcn_mfma_f32_16x16x32_f16(a1, b, acc[1][cb], 0, 0, 0);
      }
    }
  }
  #pragma unroll
  for (int rr = 0; rr < 2; ++rr){
    #pragma unroll
    for (int i = 0; i < 4; ++i){
      int row = rowBase + wid * 32 + rr * 16 + l4 * 4 + i;
      if (row < N){
        #pragma unroll
        for (int cb = 0; cb < 2; ++cb)
          h2pre[(size_t)row * 32 + cb * 16 + l15] = __float2half(acc[rr][cb][i]);
      }
    }
  }
  float sw0 = att_src2[l15], sw1 = att_src2[16 + l15];
  float dw0 = att_dst2[l15], dw1 = att_dst2[16 + l15];
  #pragma unroll
  for (int rr = 0; rr < 2; ++rr){
    #pragma unroll
    for (int i = 0; i < 4; ++i){
      float ts = acc[rr][0][i] * sw0 + acc[rr][1][i] * sw1;
      float td = acc[rr][0][i] * dw0 + acc[rr][1][i] * dw1;
      #pragma unroll
      for (int st = 8; st > 0; st >>= 1){
        ts += __shfl_xor(ts, st);
        td += __shfl_xor(td, st);
      }
      int row = rowBase + wid * 32 + rr * 16 + l4 * 4 + i;
      if (l15 == 0 && row < N){
        a_src2[row] = ts;
        a_dst2[row] = td;
      }
    }
  }
}

// ---------------- layer 2 node kernel (gather MLP 4) ----------------
__global__ __launch_bounds__(256) void node2_kernel(
    const __half* __restrict__ h2pre, const float* __restrict__ a_src2,
    const float* __restrict__ a_dst2, const int* __restrict__ offsets,
    const int* __restrict__ csr_src, const int* __restrict__ csr_eid,
    const float* __restrict__ bias2, float* __restrict__ out_h2,
    float* __restrict__ alpha2_out, int N){
  __shared__ float al_lds[4][64];
  int gid = blockIdx.x * blockDim.x + threadIdx.x;
  int n = gid >> 6, lane = gid & 63, wid = (threadIdx.x >> 6) & 3;
  if (n >= N) return;
  int off = offsets[n], deg = offsets[n + 1] - off;
  float adn = a_dst2[n];
  bool have0 = (lane < deg);
  float e0 = -INFINITY;
  if (have0) e0 = lrelu(a_src2[csr_src[off + lane]] + adn);
  float m = e0;
  for (int i = lane + 64; i < deg; i += 64)
    m = fmaxf(m, lrelu(a_src2[csr_src[off + i]] + adn));
  #pragma unroll
  for (int st = 32; st > 0; st >>= 1) m = fmaxf(m, __shfl_xor(m, st));
  float s = have0 ? __expf(e0 - m) : 0.f;
  for (int i = lane + 64; i < deg; i += 64)
    s += __expf(lrelu(a_src2[csr_src[off + i]] + adn) - m);
  #pragma unroll
  for (int st = 32; st > 0; st >>= 1) s += __shfl_xor(s, st);
  float inv = 1.f / (s + EPS_C);
  if (have0){
    float al = __expf(e0 - m) * inv;
    al_lds[wid][lane] = al;
    alpha2_out[csr_eid[off + lane]] = al;
  }
  for (int i = lane + 64; i < deg; i += 64){
    int slot = off + i;
    alpha2_out[csr_eid[slot]] = __expf(lrelu(a_src2[csr_src[slot]] + adn) - m) * inv;
  }
  int c = lane & 31, half = lane >> 5;
  int degL = deg < 64 ? deg : 64;
  float a0 = 0.f, a1 = 0.f, a2 = 0.f, a3 = 0.f;
  int j = half;
  for (; j + 6 < degL; j += 8){
    int s0i = csr_src[off + j];
    int s1i = csr_src[off + j + 2];
    int s2i = csr_src[off + j + 4];
    int s3i = csr_src[off + j + 6];
    float h0 = __half2float(h2pre[(size_t)s0i * 32 + c]);
    float h1v = __half2float(h2pre[(size_t)s1i * 32 + c]);
    float h2v = __half2float(h2pre[(size_t)s2i * 32 + c]);
    float h3v = __half2float(h2pre[(size_t)s3i * 32 + c]);
    a0 += al_lds[wid][j] * h0;
    a1 += al_lds[wid][j + 2] * h1v;
    a2 += al_lds[wid][j + 4] * h2v;
    a3 += al_lds[wid][j + 6] * h3v;
  }
  for (; j < degL; j += 2){
    int src = csr_src[off + j];
    a0 += al_lds[wid][j] * __half2float(h2pre[(size_t)src * 32 + c]);
  }
  for (; j < deg; j += 2){   // rare deg>64 tail
    int src = csr_src[off + j];
    float al = __expf(lrelu(a_src2[src] + adn) - m) * inv;
    a0 += al * __half2float(h2pre[(size_t)src * 32 + c]);
  }
  float acc = a0 + a1 + a2 + a3;
  acc += __shfl_xor(acc, 32);
  if (lane < 32) out_h2[(size_t)n * 32 + c] = acc + bias2[c];
}

extern "C" void kernel_launch(void* const* d_in, const int* in_sizes, int n_in,
                              void* d_out, int out_size, void* d_ws, size_t ws_size,
                              hipStream_t stream){
  const float* x        = (const float*)d_in[0];
  const int*   ei       = (const int*)d_in[1];
  const float* W1       = (const float*)d_in[2];
  const float* att_src1 = (const float*)d_in[3];
  const float* att_dst1 = (const float*)d_in[4];
  const float* bias1    = (const float*)d_in[5];
  const float* W2       = (const float*)d_in[6];
  const float* att_src2 = (const float*)d_in[7];
  const float* att_dst2 = (const float*)d_in[8];
  const float* bias2    = (const float*)d_in[9];
  float* out = (float*)d_out;
  (void)n_in; (void)out_size; (void)ws_size;

  const int N = in_sizes[0] / 128;
  const int E = in_sizes[1] / 2;
  const int* src = ei;
  const int* dst = ei + E;
  const int nb = (N + 255) / 256;

  char* ws = (char*)d_ws;
  size_t o = 0;
  auto alloc = [&](size_t bytes) -> void* {
    void* p = ws + o;
    o += (bytes + 255) & ~(size_t)255;
    return p;
  };
  __half* h1      = (__half*)alloc((size_t)N * 256 * 2);
  __half* x16     = (__half*)alloc((size_t)N * 128 * 2);
  __half* W1t     = (__half*)alloc((size_t)256 * 128 * 2);
  __half* W2t     = (__half*)alloc((size_t)32 * 256 * 2);
  __half* h1b     = (__half*)alloc((size_t)N * 256 * 2);
  __half* h2pre   = (__half*)alloc((size_t)N * 32 * 2);
  float*  a_src1  = (float*)alloc((size_t)N * 16);
  float*  a_dst1  = (float*)alloc((size_t)N * 16);
  float*  a_src2  = (float*)alloc((size_t)N * 4);
  float*  a_dst2  = (float*)alloc((size_t)N * 4);
  int*    deg     = (int*)alloc((size_t)N * 4);
  int*    offsets = (int*)alloc((size_t)(N + 1) * 4);
  int*    cursor  = (int*)alloc((size_t)N * 4);
  int*    csr_src = (int*)alloc((size_t)E * 4);
  int*    csr_eid = (int*)alloc((size_t)E * 4);
  int*    blockSums = (int*)alloc(256 * 4);
  int*    blockBase = (int*)alloc(256 * 4);

  const size_t OFF1 = (size_t)N * 32;
  const size_t OFF2 = OFF1 + (size_t)2 * E;
  const size_t OFF3 = OFF2 + (size_t)E * 4;
  const size_t OFF4 = OFF3 + (size_t)2 * E;

  // fused prep: x cvt | W1t cvt | W2t cvt | deg zero
  int n4 = (N * 128) / 4;
  int prepTotal = n4 + 128 * 256 + 256 * 32 + N;
  hipLaunchKernelGGL(prep_kernel, dim3((prepTotal + 255) / 256), dim3(256), 0, stream,
                     x, x16, W1, W1t, W2, W2t, deg, n4, N);
  // fused edge echo + degree count
  hipLaunchKernelGGL(edge_deg_kernel, dim3((2 * E + 255) / 256), dim3(256), 0, stream,
                     ei, out + OFF1, out + OFF3, deg, E, 2 * E);
  hipLaunchKernelGGL(scan1_kernel, dim3(nb), dim3(256), 0, stream, deg, offsets, blockSums, N);
  hipLaunchKernelGGL(scan2_kernel, dim3(1), dim3(256), 0, stream, blockSums, blockBase,
                     offsets + N, nb);
  hipLaunchKernelGGL(scan3_kernel, dim3(nb), dim3(256), 0, stream, offsets, blockBase, cursor, N);
  hipLaunchKernelGGL(scatter_kernel, dim3((E + 255) / 256), dim3(256), 0, stream,
                     src, dst, cursor, csr_src, csr_eid, E);
  hipLaunchKernelGGL(gemm1_kernel, dim3((N + 127) / 128, 4), dim3(256), 0, stream,
                     x16, W1t, att_src1, att_dst1, h1, a_src1, a_dst1, N);
  hipLaunchKernelGGL(node1_kernel, dim3((N * 64 + 255) / 256), dim3(256), 0, stream,
                     h1, (const float4*)a_src1, (const float*)a_src1, (const float4*)a_dst1,
                     offsets, csr_src, csr_eid, bias1, h1b, out + OFF2, N);
  hipLaunchKernelGGL(gemm2_kernel, dim3((N + 127) / 128), dim3(256), 0, stream,
                     h1b, W2t, att_src2, att_dst2, h2pre, a_src2, a_dst2, N);
  hipLaunchKernelGGL(node2_kernel, dim3((N * 64 + 255) / 256), dim3(256), 0, stream,
                     h2pre, a_src2, a_dst2, offsets, csr_src, csr_eid, bias2,
                     out, out + OFF4, N);
}